// Round 4
// baseline (18111.472 us; speedup 1.0000x reference)
//
#include <hip/hip_runtime.h>
#include <hip/hip_bf16.h>

#define N_NODES 50000
#define N_EDGES 1600000

// ---- monotone float<->uint encoding for atomicMax on signed floats ----
__device__ __forceinline__ unsigned fenc(float x) {
    unsigned b = __float_as_uint(x);
    return (b & 0x80000000u) ? ~b : (b | 0x80000000u);
}
__device__ __forceinline__ float fdec(unsigned u) {
    unsigned b = (u & 0x80000000u) ? (u & 0x7fffffffu) : ~u;
    return __uint_as_float(b);
}

__device__ __forceinline__ float bf16_raw_to_f32(unsigned short u) {
    return __uint_as_float(((unsigned)u) << 16);
}

// Round-to-nearest-even f32 -> bf16 raw bits.
__device__ __forceinline__ unsigned short f32_to_bf16_raw(float v) {
    unsigned u = __float_as_uint(v);
    return (unsigned short)((u + 0x7fffu + ((u >> 16) & 1u)) >> 16);
}

// Load element i of a float tensor whose storage dtype is fp32 (f=1) or bf16 (f=0).
__device__ __forceinline__ float load_elem(const void* p, size_t i, int f) {
    if (f) return ((const float*)p)[i];
    return bf16_raw_to_f32(((const unsigned short*)p)[i]);
}

__device__ __forceinline__ float dot16(const float* __restrict__ a,
                                       const float* __restrict__ b) {
    const float4* A = (const float4*)a;
    const float4* B = (const float4*)b;
    float acc = 0.f;
#pragma unroll
    for (int i = 0; i < 4; ++i) {
        float4 x = A[i], y = B[i];
        acc += x.x * y.x + x.y * y.y + x.z * y.z + x.w * y.w;
    }
    return acc;
}

// ---- dtype probe: decode even 16-bit slots of W1's raw storage as bf16.
// True bf16 weights -> max|v| ~ 0.5. fp32 storage -> even slots are random
// mantissa bits -> max|v| >> 1e4 with probability ~1. Writes flag (1=fp32).
__global__ void detect_dtype_kernel(const unsigned short* __restrict__ w1raw,
                                    int* __restrict__ flag) {
    __shared__ float red[256];
    float mx = 0.f;
    for (int i = threadIdx.x * 2; i < 16384; i += 512) {   // even slots only
        float v = fabsf(bf16_raw_to_f32(w1raw[i]));
        if (!isnan(v)) mx = fmaxf(mx, v);
    }
    red[threadIdx.x] = mx;
    __syncthreads();
    for (int s = 128; s > 0; s >>= 1) {
        if (threadIdx.x < s) red[threadIdx.x] = fmaxf(red[threadIdx.x], red[threadIdx.x + s]);
        __syncthreads();
    }
    if (threadIdx.x == 0) flag[0] = (red[0] > 1e4f) ? 1 : 0;
}

// ---- GEMM1: feat1[N,128] = h[N,128] @ W1[128,128], fp32 out ----
// Ws cached in LDS as bf16 bits (32 KB): exact in bf16 mode; <=0.4% per-weight
// rel err in fp32 mode, well under the 2% output threshold.
#define G1_ROWS 64
__global__ void gemm1_kernel(const void* __restrict__ h,
                             const void* __restrict__ W1,
                             float* __restrict__ feat1, int N,
                             const int* __restrict__ flag) {
    const int f = *flag;
    __shared__ unsigned short Ws[128 * 128];  // raw bf16 bits, 32 KB
    __shared__ float As[2 * 128];             // 1 KB
    for (int i = threadIdx.x; i < 128 * 128; i += 256)
        Ws[i] = f32_to_bf16_raw(load_elem(W1, i, f));
    int rbase0 = blockIdx.x * G1_ROWS;
    for (int r = 0; r < G1_ROWS; r += 2) {
        __syncthreads();   // iter 0: Ws ready; later: As consumers done
        int rbase = rbase0 + r;
        {
            int i = threadIdx.x;              // 256 threads stage 2 rows
            int rr = rbase + (i >> 7);
            As[i] = (rr < N) ? load_elem(h, (size_t)rr * 128 + (i & 127), f) : 0.f;
        }
        __syncthreads();
        int row = rbase + (threadIdx.x >> 7);
        int col = threadIdx.x & 127;
        if (row < N) {
            const float* a = &As[(threadIdx.x >> 7) << 7];
            float acc = 0.f;
#pragma unroll
            for (int k = 0; k < 128; ++k)
                acc += a[k] * bf16_raw_to_f32(Ws[k * 128 + col]);
            feat1[(size_t)row * 128 + col] = acc;
        }
    }
}

// ---- GEMM2: feat2[N,64] = elu(agg1[N,128]) @ W2[128,64] ----
#define G2_ROWS 64
__global__ void gemm2_kernel(const float* __restrict__ agg1,
                             const void* __restrict__ W2,
                             float* __restrict__ feat2, int N,
                             const int* __restrict__ flag) {
    const int f = *flag;
    __shared__ float Ws[128 * 64];    // fp32, 32 KB (exact in both modes)
    __shared__ float As[4 * 128];     // 2 KB
    for (int i = threadIdx.x; i < 128 * 64; i += 256)
        Ws[i] = load_elem(W2, i, f);
    int rbase0 = blockIdx.x * G2_ROWS;
    for (int r = 0; r < G2_ROWS; r += 4) {
        __syncthreads();
        int rbase = rbase0 + r;
        for (int i = threadIdx.x; i < 512; i += 256) {
            int rr = rbase + (i >> 7);
            float v = (rr < N) ? agg1[(size_t)rr * 128 + (i & 127)] : 0.f;
            As[i] = (v > 0.f) ? v : expm1f(v);   // ELU
        }
        __syncthreads();
        int row = rbase + (threadIdx.x >> 6);
        int col = threadIdx.x & 63;
        if (row < N) {
            const float* a = &As[(threadIdx.x >> 6) << 7];
            float acc = 0.f;
#pragma unroll
            for (int k = 0; k < 128; ++k)
                acc += a[k] * Ws[k * 64 + col];
            feat2[(size_t)row * 64 + col] = acc;
        }
    }
}

// ================= layer 1 edge passes: thread per (edge, head) ===========
__global__ void max1_kernel(const float* __restrict__ feat1,
                            const int* __restrict__ src,
                            const int* __restrict__ dst,
                            unsigned* __restrict__ m1, int E) {
    int gid = blockIdx.x * 256 + threadIdx.x;
    if (gid >= E * 8) return;
    int eid = gid >> 3, hd = gid & 7;
    int s = src[eid], d = dst[eid];
    float sc = dot16(feat1 + (size_t)s * 128 + hd * 16,
                     feat1 + (size_t)d * 128 + hd * 16) * 0.25f;
    atomicMax(m1 + (size_t)d * 8 + hd, fenc(sc));
}

__global__ void sum1_kernel(const float* __restrict__ feat1,
                            const int* __restrict__ src,
                            const int* __restrict__ dst,
                            const unsigned* __restrict__ m1,
                            float* __restrict__ denom1, int E) {
    int gid = blockIdx.x * 256 + threadIdx.x;
    if (gid >= E * 8) return;
    int eid = gid >> 3, hd = gid & 7;
    int s = src[eid], d = dst[eid];
    float sc = dot16(feat1 + (size_t)s * 128 + hd * 16,
                     feat1 + (size_t)d * 128 + hd * 16) * 0.25f;
    float mv = fdec(m1[(size_t)d * 8 + hd]);
    atomicAdd(denom1 + (size_t)d * 8 + hd, __expf(sc - mv));
}

__global__ void agg1_kernel(const float* __restrict__ feat1,
                            const int* __restrict__ src,
                            const int* __restrict__ dst,
                            const unsigned* __restrict__ m1,
                            const float* __restrict__ denom1,
                            float* __restrict__ agg1, int E) {
    int gid = blockIdx.x * 256 + threadIdx.x;
    if (gid >= E * 8) return;
    int eid = gid >> 3, hd = gid & 7;
    int s = src[eid], d = dst[eid];
    const float* fs = feat1 + (size_t)s * 128 + hd * 16;
    float sc = dot16(fs, feat1 + (size_t)d * 128 + hd * 16) * 0.25f;
    float mv = fdec(m1[(size_t)d * 8 + hd]);
    float a = __expf(sc - mv) / fmaxf(denom1[(size_t)d * 8 + hd], 1e-9f);
    float* ag = agg1 + (size_t)d * 128 + hd * 16;
    const float4* FS = (const float4*)fs;
#pragma unroll
    for (int i = 0; i < 4; ++i) {
        float4 v = FS[i];
        atomicAdd(ag + 4 * i + 0, a * v.x);
        atomicAdd(ag + 4 * i + 1, a * v.y);
        atomicAdd(ag + 4 * i + 2, a * v.z);
        atomicAdd(ag + 4 * i + 3, a * v.w);
    }
}

// ========= layer 2 edge passes: 4 lanes per edge (16 dims each) ===========
__global__ void max2_kernel(const float* __restrict__ feat2,
                            const int* __restrict__ src,
                            const int* __restrict__ dst,
                            unsigned* __restrict__ m2, int E) {
    int gid = blockIdx.x * 256 + threadIdx.x;
    if (gid >= E * 4) return;
    int eid = gid >> 2, q = gid & 3;
    int s = src[eid], d = dst[eid];
    float acc = dot16(feat2 + (size_t)s * 64 + q * 16,
                      feat2 + (size_t)d * 64 + q * 16);
    acc += __shfl_xor(acc, 1);
    acc += __shfl_xor(acc, 2);
    if (q == 0) atomicMax(m2 + d, fenc(acc * 0.125f));
}

__global__ void sum2_kernel(const float* __restrict__ feat2,
                            const int* __restrict__ src,
                            const int* __restrict__ dst,
                            const unsigned* __restrict__ m2,
                            float* __restrict__ denom2, int E) {
    int gid = blockIdx.x * 256 + threadIdx.x;
    if (gid >= E * 4) return;
    int eid = gid >> 2, q = gid & 3;
    int s = src[eid], d = dst[eid];
    float acc = dot16(feat2 + (size_t)s * 64 + q * 16,
                      feat2 + (size_t)d * 64 + q * 16);
    acc += __shfl_xor(acc, 1);
    acc += __shfl_xor(acc, 2);
    if (q == 0) {
        float sc = acc * 0.125f;
        atomicAdd(denom2 + d, __expf(sc - fdec(m2[d])));
    }
}

__global__ void agg2_kernel(const float* __restrict__ feat2,
                            const int* __restrict__ src,
                            const int* __restrict__ dst,
                            const unsigned* __restrict__ m2,
                            const float* __restrict__ denom2,
                            float* __restrict__ agg2, int E) {
    int gid = blockIdx.x * 256 + threadIdx.x;
    if (gid >= E * 4) return;
    int eid = gid >> 2, q = gid & 3;
    int s = src[eid], d = dst[eid];
    const float* fs = feat2 + (size_t)s * 64 + q * 16;
    float acc = dot16(fs, feat2 + (size_t)d * 64 + q * 16);
    acc += __shfl_xor(acc, 1);
    acc += __shfl_xor(acc, 2);   // all 4 lanes hold the full dot
    float sc = acc * 0.125f;
    float a = __expf(sc - fdec(m2[d])) / fmaxf(denom2[d], 1e-9f);
    float* ag = agg2 + (size_t)d * 64 + q * 16;
    const float4* FS = (const float4*)fs;
#pragma unroll
    for (int i = 0; i < 4; ++i) {
        float4 v = FS[i];
        atomicAdd(ag + 4 * i + 0, a * v.x);
        atomicAdd(ag + 4 * i + 1, a * v.y);
        atomicAdd(ag + 4 * i + 2, a * v.z);
        atomicAdd(ag + 4 * i + 3, a * v.w);
    }
}

__global__ void finalize_kernel(const float* __restrict__ agg2,
                                void* __restrict__ out, int n,
                                const int* __restrict__ flag) {
    const int f = *flag;
    int i = blockIdx.x * 256 + threadIdx.x;
    if (i >= n) return;
    float v = agg2[i];
    if (f) ((float*)out)[i] = v;
    else   ((__hip_bfloat16*)out)[i] = __float2bfloat16(v);
}

extern "C" void kernel_launch(void* const* d_in, const int* in_sizes, int n_in,
                              void* d_out, int out_size, void* d_ws, size_t ws_size,
                              hipStream_t stream) {
    const void* h  = d_in[0];
    const void* W1 = d_in[1];
    const void* W2 = d_in[2];
    const int* src = (const int*)d_in[3];
    const int* dst = (const int*)d_in[4];

    float* ws = (float*)d_ws;
    // Layout (floats), peak 13.6M floats + flag = ~54.4 MB:
    //   [0,     6.4M)  feat1 [N,128]   (layer 2: feat2 [N,64] at 0, agg2 at +3.2M)
    //   [6.4M,  6.8M)  m1 [N,8] uint   (layer 2: m2 reuse)
    //   [6.8M,  7.2M)  denom1 [N,8]    (layer 2: denom2 reuse)
    //   [7.2M, 13.6M)  agg1 [N,128]
    //   [13.6M]        dtype flag (int)
    float*    feat1  = ws;
    unsigned* m1     = (unsigned*)(ws + 6400000);
    float*    denom1 = ws + 6800000;
    float*    agg1   = ws + 7200000;
    int*      flag   = (int*)(ws + 13600000);
    float*    feat2  = ws;                 // overwrites feat1 (dead by then)
    float*    agg2   = ws + 3200000;
    unsigned* m2     = m1;
    float*    denom2 = denom1;

    detect_dtype_kernel<<<1, 256, 0, stream>>>((const unsigned short*)W1, flag);

    // zero m1 + denom1 + agg1 (contiguous 7.2M floats)
    (void)hipMemsetAsync(ws + 6400000, 0, (size_t)7200000 * 4, stream);

    gemm1_kernel<<<(N_NODES + G1_ROWS - 1) / G1_ROWS, 256, 0, stream>>>(h, W1, feat1, N_NODES, flag);
    max1_kernel<<<(N_EDGES * 8) / 256, 256, 0, stream>>>(feat1, src, dst, m1, N_EDGES);
    sum1_kernel<<<(N_EDGES * 8) / 256, 256, 0, stream>>>(feat1, src, dst, m1, denom1, N_EDGES);
    agg1_kernel<<<(N_EDGES * 8) / 256, 256, 0, stream>>>(feat1, src, dst, m1, denom1, agg1, N_EDGES);

    // feat1 dead from here; gemm2 writes feat2 over it
    gemm2_kernel<<<(N_NODES + G2_ROWS - 1) / G2_ROWS, 256, 0, stream>>>(agg1, W2, feat2, N_NODES, flag);

    // zero m2 + denom2 (0.8M floats) and agg2 (3.2M floats)
    (void)hipMemsetAsync(ws + 6400000, 0, (size_t)800000 * 4, stream);
    (void)hipMemsetAsync(ws + 3200000, 0, (size_t)3200000 * 4, stream);

    max2_kernel<<<(N_EDGES * 4) / 256, 256, 0, stream>>>(feat2, src, dst, m2, N_EDGES);
    sum2_kernel<<<(N_EDGES * 4) / 256, 256, 0, stream>>>(feat2, src, dst, m2, denom2, N_EDGES);
    agg2_kernel<<<(N_EDGES * 4) / 256, 256, 0, stream>>>(feat2, src, dst, m2, denom2, agg2, N_EDGES);

    finalize_kernel<<<(out_size + 255) / 256, 256, 0, stream>>>(agg2, d_out, out_size, flag);
}

// Round 5
// 1072.427 us; speedup vs baseline: 16.8883x; 16.8883x over previous
//
#include <hip/hip_runtime.h>
#include <hip/hip_bf16.h>

#define N_NODES 50000
#define N_EDGES 1600000

__device__ __forceinline__ float bf16_raw_to_f32(unsigned short u) {
    return __uint_as_float(((unsigned)u) << 16);
}
__device__ __forceinline__ unsigned short f32_to_bf16_raw(float v) {
    unsigned u = __float_as_uint(v);
    return (unsigned short)((u + 0x7fffu + ((u >> 16) & 1u)) >> 16);
}
// Load element i of a float tensor stored fp32 (f=1) or bf16 (f=0).
__device__ __forceinline__ float load_elem(const void* p, size_t i, int f) {
    if (f) return ((const float*)p)[i];
    return bf16_raw_to_f32(((const unsigned short*)p)[i]);
}

// ---- dtype probe (see R3 notes): decode even 16-bit slots of W1 as bf16;
// fp32 storage shows |v| >> 1e4 with prob ~1. flag=1 -> fp32 storage.
__global__ void detect_dtype_kernel(const unsigned short* __restrict__ w1raw,
                                    int* __restrict__ flag) {
    __shared__ float red[256];
    float mx = 0.f;
    for (int i = threadIdx.x * 2; i < 16384; i += 512) {
        float v = fabsf(bf16_raw_to_f32(w1raw[i]));
        if (!isnan(v)) mx = fmaxf(mx, v);
    }
    red[threadIdx.x] = mx;
    __syncthreads();
    for (int s = 128; s > 0; s >>= 1) {
        if (threadIdx.x < s) red[threadIdx.x] = fmaxf(red[threadIdx.x], red[threadIdx.x + s]);
        __syncthreads();
    }
    if (threadIdx.x == 0) flag[0] = (red[0] > 1e4f) ? 1 : 0;
}

// ======================= CSR build (by dst) =======================
__global__ void count_kernel(const int* __restrict__ dst, int* __restrict__ cnt, int E) {
    int e = blockIdx.x * 256 + threadIdx.x;
    if (e < E) atomicAdd(cnt + dst[e], 1);
}

// Single-block exclusive scan of deg[0..n) -> start[0..n], zeroes cursor.
__global__ void scan_kernel(const int* __restrict__ deg, int* __restrict__ start,
                            int* __restrict__ cursor, int n) {
    __shared__ int part[1024];
    int t = threadIdx.x;
    int chunk = (n + 1023) / 1024;
    int lo = t * chunk, hi = min(lo + chunk, n);
    int s = 0;
    for (int i = lo; i < hi; ++i) s += deg[i];
    part[t] = s;
    __syncthreads();
    for (int off = 1; off < 1024; off <<= 1) {
        int v = (t >= off) ? part[t - off] : 0;
        __syncthreads();
        part[t] += v;
        __syncthreads();
    }
    int base = (t == 0) ? 0 : part[t - 1];
    for (int i = lo; i < hi; ++i) {
        start[i] = base;
        base += deg[i];       // read before cursor write (same array is safe)
        cursor[i] = 0;
    }
    if (t == 1023) start[n] = part[1023];
}

__global__ void fill_kernel(const int* __restrict__ dst, const int* __restrict__ start,
                            int* __restrict__ cursor, int* __restrict__ edge_list, int E) {
    int e = blockIdx.x * 256 + threadIdx.x;
    if (e >= E) return;
    int d = dst[e];
    int p = atomicAdd(cursor + d, 1);
    edge_list[start[d] + p] = e;
}

// ---- GEMM1: feat1[N,128] = h[N,128] @ W1[128,128], fp32 out ----
#define G1_ROWS 64
__global__ void gemm1_kernel(const void* __restrict__ h,
                             const void* __restrict__ W1,
                             float* __restrict__ feat1, int N,
                             const int* __restrict__ flag) {
    const int f = *flag;
    __shared__ unsigned short Ws[128 * 128];  // bf16 bits, 32 KB
    __shared__ float As[2 * 128];
    for (int i = threadIdx.x; i < 128 * 128; i += 256)
        Ws[i] = f32_to_bf16_raw(load_elem(W1, i, f));
    int rbase0 = blockIdx.x * G1_ROWS;
    for (int r = 0; r < G1_ROWS; r += 2) {
        __syncthreads();
        int rbase = rbase0 + r;
        {
            int i = threadIdx.x;
            int rr = rbase + (i >> 7);
            As[i] = (rr < N) ? load_elem(h, (size_t)rr * 128 + (i & 127), f) : 0.f;
        }
        __syncthreads();
        int row = rbase + (threadIdx.x >> 7);
        int col = threadIdx.x & 127;
        if (row < N) {
            const float* a = &As[(threadIdx.x >> 7) << 7];
            float acc = 0.f;
#pragma unroll
            for (int k = 0; k < 128; ++k)
                acc += a[k] * bf16_raw_to_f32(Ws[k * 128 + col]);
            feat1[(size_t)row * 128 + col] = acc;
        }
    }
}

// ---- GEMM2: feat2[N,64] = elu(agg1[N,128]) @ W2[128,64] ----
#define G2_ROWS 64
__global__ void gemm2_kernel(const float* __restrict__ agg1,
                             const void* __restrict__ W2,
                             float* __restrict__ feat2, int N,
                             const int* __restrict__ flag) {
    const int f = *flag;
    __shared__ float Ws[128 * 64];
    __shared__ float As[4 * 128];
    for (int i = threadIdx.x; i < 128 * 64; i += 256)
        Ws[i] = load_elem(W2, i, f);
    int rbase0 = blockIdx.x * G2_ROWS;
    for (int r = 0; r < G2_ROWS; r += 4) {
        __syncthreads();
        int rbase = rbase0 + r;
        for (int i = threadIdx.x; i < 512; i += 256) {
            int rr = rbase + (i >> 7);
            float v = (rr < N) ? agg1[(size_t)rr * 128 + (i & 127)] : 0.f;
            As[i] = (v > 0.f) ? v : expm1f(v);   // ELU
        }
        __syncthreads();
        int row = rbase + (threadIdx.x >> 6);
        int col = threadIdx.x & 63;
        if (row < N) {
            const float* a = &As[(threadIdx.x >> 6) << 7];
            float acc = 0.f;
#pragma unroll
            for (int k = 0; k < 128; ++k)
                acc += a[k] * Ws[k * 64 + col];
            feat2[(size_t)row * 64 + col] = acc;
        }
    }
}

// ======= layer 1 fused GAT: one wave per dst node, online softmax =======
// lane l holds dims (2l, 2l+1); head h = lanes [8h, 8h+8); no atomics.
__global__ void gat1_kernel(const float* __restrict__ feat1,
                            const int* __restrict__ src,
                            const int* __restrict__ start,
                            const int* __restrict__ edge_list,
                            float* __restrict__ agg1, int N) {
    int wave = blockIdx.x * 4 + (threadIdx.x >> 6);
    if (wave >= N) return;
    int lane = threadIdx.x & 63;
    const int d = wave;
    const float2* F = (const float2*)feat1;
    float2 fd = F[(size_t)d * 64 + lane];

    float m = -__builtin_inff(), l = 0.f, a0 = 0.f, a1 = 0.f;
    int e0 = start[d], e1 = start[d + 1];
    for (int idx = e0; idx < e1; ++idx) {
        int e = edge_list[idx];
        int s = src[e];
        float2 fs = F[(size_t)s * 64 + lane];
        float p = fd.x * fs.x + fd.y * fs.y;
        p += __shfl_xor(p, 1);
        p += __shfl_xor(p, 2);
        p += __shfl_xor(p, 4);          // head-group (8 lanes) dot
        float sc = p * 0.25f;           // 16^-0.5
        float mn = fmaxf(m, sc);
        float sf = __expf(m - mn);      // exp(-inf)=0 on first edge
        float w  = __expf(sc - mn);
        a0 = a0 * sf + w * fs.x;
        a1 = a1 * sf + w * fs.y;
        l  = l  * sf + w;
        m  = mn;
    }
    float rcp = 1.f / fmaxf(l, 1e-9f);
    float2 o; o.x = a0 * rcp; o.y = a1 * rcp;
    ((float2*)agg1)[(size_t)d * 64 + lane] = o;
}

// ======= layer 2 fused GAT: one wave per dst node, 1 head x 64 dims ======
__global__ void gat2_kernel(const float* __restrict__ feat2,
                            const int* __restrict__ src,
                            const int* __restrict__ start,
                            const int* __restrict__ edge_list,
                            float* __restrict__ agg2, int N) {
    int wave = blockIdx.x * 4 + (threadIdx.x >> 6);
    if (wave >= N) return;
    int lane = threadIdx.x & 63;
    const int d = wave;
    float fd = feat2[(size_t)d * 64 + lane];

    float m = -__builtin_inff(), l = 0.f, a = 0.f;
    int e0 = start[d], e1 = start[d + 1];
    for (int idx = e0; idx < e1; ++idx) {
        int e = edge_list[idx];
        int s = src[e];
        float fs = feat2[(size_t)s * 64 + lane];
        float p = fd * fs;
        p += __shfl_xor(p, 1);
        p += __shfl_xor(p, 2);
        p += __shfl_xor(p, 4);
        p += __shfl_xor(p, 8);
        p += __shfl_xor(p, 16);
        p += __shfl_xor(p, 32);         // full-wave dot
        float sc = p * 0.125f;          // 64^-0.5
        float mn = fmaxf(m, sc);
        float sf = __expf(m - mn);
        float w  = __expf(sc - mn);
        a = a * sf + w * fs;
        l = l * sf + w;
        m = mn;
    }
    float rcp = 1.f / fmaxf(l, 1e-9f);
    agg2[(size_t)d * 64 + lane] = a * rcp;
}

__global__ void finalize_kernel(const float* __restrict__ agg2,
                                void* __restrict__ out, int n,
                                const int* __restrict__ flag) {
    const int f = *flag;
    int i = blockIdx.x * 256 + threadIdx.x;
    if (i >= n) return;
    float v = agg2[i];
    if (f) ((float*)out)[i] = v;
    else   ((__hip_bfloat16*)out)[i] = __float2bfloat16(v);
}

extern "C" void kernel_launch(void* const* d_in, const int* in_sizes, int n_in,
                              void* d_out, int out_size, void* d_ws, size_t ws_size,
                              hipStream_t stream) {
    const void* h  = d_in[0];
    const void* W1 = d_in[1];
    const void* W2 = d_in[2];
    const int* src = (const int*)d_in[3];
    const int* dst = (const int*)d_in[4];

    float* ws = (float*)d_ws;
    // Layout (4-byte units), peak ~14.5M = 58.0 MB:
    //   [0,      6.4M)   feat1 [N,128]   (layer 2: feat2 [N,64] at 0)
    //   [3.2M,   6.4M)   agg2 [N,64]     (after feat1 dead)
    //   [6.4M,  12.8M)   agg1 [N,128]
    //   [12.8M, 14.4M)   edge_list [E] int
    //   [14.4M, 14.45M)  start [N+1] int
    //   [14.46M,14.51M)  cursor/deg [N] int
    //   [14.52M]         dtype flag
    float* feat1     = ws;
    float* agg1      = ws + 6400000;
    int*   edge_list = (int*)(ws + 12800000);
    int*   start     = (int*)(ws + 14400000);
    int*   cursor    = (int*)(ws + 14460000);
    int*   flag      = (int*)(ws + 14520000);
    float* feat2     = ws;
    float* agg2      = ws + 3200000;

    detect_dtype_kernel<<<1, 256, 0, stream>>>((const unsigned short*)W1, flag);

    // ---- CSR by dst (shared by both layers) ----
    (void)hipMemsetAsync(cursor, 0, (size_t)N_NODES * 4, stream);
    count_kernel<<<N_EDGES / 256, 256, 0, stream>>>(dst, cursor, N_EDGES);
    scan_kernel<<<1, 1024, 0, stream>>>(cursor, start, cursor, N_NODES);
    fill_kernel<<<N_EDGES / 256, 256, 0, stream>>>(dst, start, cursor, edge_list, N_EDGES);

    gemm1_kernel<<<(N_NODES + G1_ROWS - 1) / G1_ROWS, 256, 0, stream>>>(h, W1, feat1, N_NODES, flag);
    gat1_kernel<<<(N_NODES + 3) / 4, 256, 0, stream>>>(feat1, src, start, edge_list, agg1, N_NODES);
    gemm2_kernel<<<(N_NODES + G2_ROWS - 1) / G2_ROWS, 256, 0, stream>>>(agg1, W2, feat2, N_NODES, flag);
    gat2_kernel<<<(N_NODES + 3) / 4, 256, 0, stream>>>(feat2, src, start, edge_list, agg2, N_NODES);
    finalize_kernel<<<(out_size + 255) / 256, 256, 0, stream>>>(agg2, d_out, out_size, flag);
}

// Round 7
// 869.589 us; speedup vs baseline: 20.8276x; 1.2333x over previous
//
#include <hip/hip_runtime.h>
#include <hip/hip_bf16.h>

#define N_NODES 50000
#define N_EDGES 1600000

__device__ __forceinline__ float bf16_raw_to_f32(unsigned short u) {
    return __uint_as_float(((unsigned)u) << 16);
}
__device__ __forceinline__ unsigned short f32_to_bf16_raw(float v) {
    unsigned u = __float_as_uint(v);
    return (unsigned short)((u + 0x7fffu + ((u >> 16) & 1u)) >> 16);
}
// Load element i of a float tensor stored fp32 (f=1) or bf16 (f=0).
__device__ __forceinline__ float load_elem(const void* p, size_t i, int f) {
    if (f) return ((const float*)p)[i];
    return bf16_raw_to_f32(((const unsigned short*)p)[i]);
}

// ---- dtype probe: decode even 16-bit slots of W1 as bf16; fp32 storage
// shows |v| >> 1e4 with prob ~1. flag=1 -> fp32 storage. (verified R4)
__global__ void detect_dtype_kernel(const unsigned short* __restrict__ w1raw,
                                    int* __restrict__ flag) {
    __shared__ float red[256];
    float mx = 0.f;
    for (int i = threadIdx.x * 2; i < 16384; i += 512) {
        float v = fabsf(bf16_raw_to_f32(w1raw[i]));
        if (!isnan(v)) mx = fmaxf(mx, v);
    }
    red[threadIdx.x] = mx;
    __syncthreads();
    for (int s = 128; s > 0; s >>= 1) {
        if (threadIdx.x < s) red[threadIdx.x] = fmaxf(red[threadIdx.x], red[threadIdx.x + s]);
        __syncthreads();
    }
    if (threadIdx.x == 0) flag[0] = (red[0] > 1e4f) ? 1 : 0;
}

// ======================= CSR build (by dst) =======================
__global__ void count_kernel(const int* __restrict__ dst, int* __restrict__ cnt, int E) {
    int e = blockIdx.x * 256 + threadIdx.x;
    if (e < E) atomicAdd(cnt + dst[e], 1);
}

// Single-block exclusive scan of deg[0..n) -> start[0..n], zeroes cursor.
__global__ void scan_kernel(const int* __restrict__ deg, int* __restrict__ start,
                            int* __restrict__ cursor, int n) {
    __shared__ int part[1024];
    int t = threadIdx.x;
    int chunk = (n + 1023) / 1024;
    int lo = t * chunk, hi = min(lo + chunk, n);
    int s = 0;
    for (int i = lo; i < hi; ++i) s += deg[i];
    part[t] = s;
    __syncthreads();
    for (int off = 1; off < 1024; off <<= 1) {
        int v = (t >= off) ? part[t - off] : 0;
        __syncthreads();
        part[t] += v;
        __syncthreads();
    }
    int base = (t == 0) ? 0 : part[t - 1];
    for (int i = lo; i < hi; ++i) {
        start[i] = base;
        base += deg[i];
        cursor[i] = 0;
    }
    if (t == 1023) start[n] = part[1023];
}

// Stores the SRC NODE ID (not edge id) -> one less indirection in gat loops.
__global__ void fill_kernel(const int* __restrict__ dst, const int* __restrict__ src,
                            const int* __restrict__ start,
                            int* __restrict__ cursor, int* __restrict__ csr_src, int E) {
    int e = blockIdx.x * 256 + threadIdx.x;
    if (e >= E) return;
    int d = dst[e];
    int p = atomicAdd(cursor + d, 1);
    csr_src[start[d] + p] = src[e];
}

// ---- GEMM1: feat1[N,128] (bf16) = h[N,128] @ W1[128,128] ----
#define G1_ROWS 64
__global__ void gemm1_kernel(const void* __restrict__ h,
                             const void* __restrict__ W1,
                             unsigned short* __restrict__ feat1, int N,
                             const int* __restrict__ flag) {
    const int f = *flag;
    __shared__ unsigned short Ws[128 * 128];  // bf16 bits, 32 KB
    __shared__ float As[2 * 128];
    for (int i = threadIdx.x; i < 128 * 128; i += 256)
        Ws[i] = f32_to_bf16_raw(load_elem(W1, i, f));
    int rbase0 = blockIdx.x * G1_ROWS;
    for (int r = 0; r < G1_ROWS; r += 2) {
        __syncthreads();
        int rbase = rbase0 + r;
        {
            int i = threadIdx.x;
            int rr = rbase + (i >> 7);
            As[i] = (rr < N) ? load_elem(h, (size_t)rr * 128 + (i & 127), f) : 0.f;
        }
        __syncthreads();
        int row = rbase + (threadIdx.x >> 7);
        int col = threadIdx.x & 127;
        if (row < N) {
            const float* a = &As[(threadIdx.x >> 7) << 7];
            float acc = 0.f;
#pragma unroll
            for (int k = 0; k < 128; ++k)
                acc += a[k] * bf16_raw_to_f32(Ws[k * 128 + col]);
            feat1[(size_t)row * 128 + col] = f32_to_bf16_raw(acc);
        }
    }
}

// ---- GEMM2: feat2[N,64] (bf16) = elu(agg1[N,128]) @ W2[128,64] ----
#define G2_ROWS 64
__global__ void gemm2_kernel(const float* __restrict__ agg1,
                             const void* __restrict__ W2,
                             unsigned short* __restrict__ feat2, int N,
                             const int* __restrict__ flag) {
    const int f = *flag;
    __shared__ float Ws[128 * 64];
    __shared__ float As[4 * 128];
    for (int i = threadIdx.x; i < 128 * 64; i += 256)
        Ws[i] = load_elem(W2, i, f);
    int rbase0 = blockIdx.x * G2_ROWS;
    for (int r = 0; r < G2_ROWS; r += 4) {
        __syncthreads();
        int rbase = rbase0 + r;
        for (int i = threadIdx.x; i < 512; i += 256) {
            int rr = rbase + (i >> 7);
            float v = (rr < N) ? agg1[(size_t)rr * 128 + (i & 127)] : 0.f;
            As[i] = (v > 0.f) ? v : expm1f(v);   // ELU
        }
        __syncthreads();
        int row = rbase + (threadIdx.x >> 6);
        int col = threadIdx.x & 63;
        if (row < N) {
            const float* a = &As[(threadIdx.x >> 6) << 7];
            float acc = 0.f;
#pragma unroll
            for (int k = 0; k < 128; ++k)
                acc += a[k] * Ws[k * 64 + col];
            feat2[(size_t)row * 64 + col] = f32_to_bf16_raw(acc);
        }
    }
}

// ======= layer 1 fused GAT: one wave per dst, ONLINE max-shift softmax ====
// (R5-proven numerics; R6's plain-exp + batched shfl loads are reverted.)
// lane l holds dims (2l,2l+1) packed bf16x2; head h = lanes [8h,8h+8).
__global__ void gat1_kernel(const unsigned short* __restrict__ feat1,
                            const int* __restrict__ csr_src,
                            const int* __restrict__ start,
                            float* __restrict__ agg1, int N) {
    int wave = blockIdx.x * 4 + (threadIdx.x >> 6);
    if (wave >= N) return;
    int lane = threadIdx.x & 63;
    const unsigned* F = (const unsigned*)feat1;   // 2 bf16 per uint
    unsigned fdu = F[(size_t)wave * 64 + lane];
    float fdx = bf16_raw_to_f32((unsigned short)(fdu & 0xffffu));
    float fdy = bf16_raw_to_f32((unsigned short)(fdu >> 16));

    float m = -__builtin_inff(), l = 0.f, a0 = 0.f, a1 = 0.f;
    int e0 = start[wave], e1 = start[wave + 1];
    for (int idx = e0; idx < e1; ++idx) {
        int s = csr_src[idx];                 // wave-uniform scalar load
        unsigned fsu = F[(size_t)s * 64 + lane];
        float fx = bf16_raw_to_f32((unsigned short)(fsu & 0xffffu));
        float fy = bf16_raw_to_f32((unsigned short)(fsu >> 16));
        float p = fdx * fx + fdy * fy;
        p += __shfl_xor(p, 1);
        p += __shfl_xor(p, 2);
        p += __shfl_xor(p, 4);                // 8-lane head dot
        float sc = p * 0.25f;                 // 16^-0.5
        float mn = fmaxf(m, sc);
        float sf = __expf(m - mn);            // exp(-inf)=0 on first edge
        float w  = __expf(sc - mn);
        a0 = a0 * sf + w * fx;
        a1 = a1 * sf + w * fy;
        l  = l  * sf + w;
        m  = mn;
    }
    float rcp = 1.f / fmaxf(l, 1e-9f);
    float2 o; o.x = a0 * rcp; o.y = a1 * rcp;
    ((float2*)agg1)[(size_t)wave * 64 + lane] = o;
}

// ======= layer 2 fused GAT: one wave per dst, 1 head x 64 dims =======
__global__ void gat2_kernel(const unsigned short* __restrict__ feat2,
                            const int* __restrict__ csr_src,
                            const int* __restrict__ start,
                            float* __restrict__ agg2, int N) {
    int wave = blockIdx.x * 4 + (threadIdx.x >> 6);
    if (wave >= N) return;
    int lane = threadIdx.x & 63;
    float fd = bf16_raw_to_f32(feat2[(size_t)wave * 64 + lane]);

    float m = -__builtin_inff(), l = 0.f, a = 0.f;
    int e0 = start[wave], e1 = start[wave + 1];
    for (int idx = e0; idx < e1; ++idx) {
        int s = csr_src[idx];                 // wave-uniform scalar load
        float fs = bf16_raw_to_f32(feat2[(size_t)s * 64 + lane]);
        float p = fd * fs;
        p += __shfl_xor(p, 1);
        p += __shfl_xor(p, 2);
        p += __shfl_xor(p, 4);
        p += __shfl_xor(p, 8);
        p += __shfl_xor(p, 16);
        p += __shfl_xor(p, 32);               // full-wave dot
        float sc = p * 0.125f;                // 64^-0.5
        float mn = fmaxf(m, sc);
        float sf = __expf(m - mn);
        float w  = __expf(sc - mn);
        a = a * sf + w * fs;
        l = l * sf + w;
        m = mn;
    }
    float rcp = 1.f / fmaxf(l, 1e-9f);
    agg2[(size_t)wave * 64 + lane] = a * rcp;
}

__global__ void finalize_kernel(const float* __restrict__ agg2,
                                void* __restrict__ out, int n,
                                const int* __restrict__ flag) {
    const int f = *flag;
    int i = blockIdx.x * 256 + threadIdx.x;
    if (i >= n) return;
    float v = agg2[i];
    if (f) ((float*)out)[i] = v;
    else   ((__hip_bfloat16*)out)[i] = __float2bfloat16(v);
}

extern "C" void kernel_launch(void* const* d_in, const int* in_sizes, int n_in,
                              void* d_out, int out_size, void* d_ws, size_t ws_size,
                              hipStream_t stream) {
    const void* h  = d_in[0];
    const void* W1 = d_in[1];
    const void* W2 = d_in[2];
    const int* src = (const int*)d_in[3];
    const int* dst = (const int*)d_in[4];

    float* ws = (float*)d_ws;
    // Layout (4-byte words), peak ~11.4M words = 45.3 MB:
    //   [0,     3.2M)   feat1 [N,128] bf16 (6.4M ushort)
    //   [3.2M,  9.6M)   agg1 [N,128] fp32
    //   [0,     0.8M)   feat2 [N,64] bf16  (reuses feat1 space after dead)
    //   [1.6M,  4.8M)   agg2 [N,64] fp32   (agg1 dead by then)
    //   [9.6M, 11.2M)   csr_src [E] int
    //   [11.2M,11.26M)  start [N+1] int
    //   [11.26M,11.32M) cursor/deg [N] int
    //   [11.33M]        dtype flag
    unsigned short* feat1 = (unsigned short*)ws;
    float* agg1           = ws + 3200000;
    unsigned short* feat2 = (unsigned short*)ws;      // after feat1 dead
    float* agg2           = ws + 1600000;             // after agg1 consumed
    int*   csr_src        = (int*)(ws + 9600000);
    int*   start          = (int*)(ws + 11200000);
    int*   cursor         = (int*)(ws + 11260000);
    int*   flag           = (int*)(ws + 11330000);

    detect_dtype_kernel<<<1, 256, 0, stream>>>((const unsigned short*)W1, flag);

    // ---- CSR by dst (shared by both layers), storing src ids ----
    (void)hipMemsetAsync(cursor, 0, (size_t)N_NODES * 4, stream);
    count_kernel<<<N_EDGES / 256, 256, 0, stream>>>(dst, cursor, N_EDGES);
    scan_kernel<<<1, 1024, 0, stream>>>(cursor, start, cursor, N_NODES);
    fill_kernel<<<N_EDGES / 256, 256, 0, stream>>>(dst, src, start, cursor, csr_src, N_EDGES);

    gemm1_kernel<<<(N_NODES + G1_ROWS - 1) / G1_ROWS, 256, 0, stream>>>(h, W1, feat1, N_NODES, flag);
    gat1_kernel<<<(N_NODES + 3) / 4, 256, 0, stream>>>(feat1, csr_src, start, agg1, N_NODES);
    gemm2_kernel<<<(N_NODES + G2_ROWS - 1) / G2_ROWS, 256, 0, stream>>>(agg1, W2, feat2, N_NODES, flag);
    gat2_kernel<<<(N_NODES + 3) / 4, 256, 0, stream>>>(feat2, csr_src, start, agg2, N_NODES);
    finalize_kernel<<<(out_size + 255) / 256, 256, 0, stream>>>(agg2, d_out, out_size, flag);
}

// Round 8
// 731.694 us; speedup vs baseline: 24.7528x; 1.1885x over previous
//
#include <hip/hip_runtime.h>
#include <hip/hip_bf16.h>

#define N_NODES 50000
#define N_EDGES 1600000

__device__ __forceinline__ float bf16_raw_to_f32(unsigned short u) {
    return __uint_as_float(((unsigned)u) << 16);
}
__device__ __forceinline__ unsigned short f32_to_bf16_raw(float v) {
    unsigned u = __float_as_uint(v);
    return (unsigned short)((u + 0x7fffu + ((u >> 16) & 1u)) >> 16);
}
// Load element i of a float tensor stored fp32 (f=1) or bf16 (f=0).
__device__ __forceinline__ float load_elem(const void* p, size_t i, int f) {
    if (f) return ((const float*)p)[i];
    return bf16_raw_to_f32(((const unsigned short*)p)[i]);
}

// ---- dtype probe: decode even 16-bit slots of W1 as bf16; fp32 storage
// shows |v| >> 1e4 with prob ~1. flag=1 -> fp32 storage. (verified R4)
__global__ void detect_dtype_kernel(const unsigned short* __restrict__ w1raw,
                                    int* __restrict__ flag) {
    __shared__ float red[256];
    float mx = 0.f;
    for (int i = threadIdx.x * 2; i < 16384; i += 512) {
        float v = fabsf(bf16_raw_to_f32(w1raw[i]));
        if (!isnan(v)) mx = fmaxf(mx, v);
    }
    red[threadIdx.x] = mx;
    __syncthreads();
    for (int s = 128; s > 0; s >>= 1) {
        if (threadIdx.x < s) red[threadIdx.x] = fmaxf(red[threadIdx.x], red[threadIdx.x + s]);
        __syncthreads();
    }
    if (threadIdx.x == 0) flag[0] = (red[0] > 1e4f) ? 1 : 0;
}

// ======================= CSR build (by dst) =======================
__global__ void count_kernel(const int* __restrict__ dst, int* __restrict__ cnt, int E) {
    int e = blockIdx.x * 256 + threadIdx.x;
    if (e < E) atomicAdd(cnt + dst[e], 1);
}

// Single-block exclusive scan of deg[0..n) -> start[0..n], zeroes cursor.
__global__ void scan_kernel(const int* __restrict__ deg, int* __restrict__ start,
                            int* __restrict__ cursor, int n) {
    __shared__ int part[1024];
    int t = threadIdx.x;
    int chunk = (n + 1023) / 1024;
    int lo = t * chunk, hi = min(lo + chunk, n);
    int s = 0;
    for (int i = lo; i < hi; ++i) s += deg[i];
    part[t] = s;
    __syncthreads();
    for (int off = 1; off < 1024; off <<= 1) {
        int v = (t >= off) ? part[t - off] : 0;
        __syncthreads();
        part[t] += v;
        __syncthreads();
    }
    int base = (t == 0) ? 0 : part[t - 1];
    for (int i = lo; i < hi; ++i) {
        start[i] = base;
        base += deg[i];
        cursor[i] = 0;
    }
    if (t == 1023) start[n] = part[1023];
}

// Stores the SRC NODE ID (not edge id) -> one less indirection in gat loops.
__global__ void fill_kernel(const int* __restrict__ dst, const int* __restrict__ src,
                            const int* __restrict__ start,
                            int* __restrict__ cursor, int* __restrict__ csr_src, int E) {
    int e = blockIdx.x * 256 + threadIdx.x;
    if (e >= E) return;
    int d = dst[e];
    int p = atomicAdd(cursor + d, 1);
    csr_src[start[d] + p] = src[e];
}

// ---- GEMM1: feat1[N,128] (bf16) = h[N,128] @ W1[128,128] ----
#define G1_ROWS 64
__global__ void gemm1_kernel(const void* __restrict__ h,
                             const void* __restrict__ W1,
                             unsigned short* __restrict__ feat1, int N,
                             const int* __restrict__ flag) {
    const int f = *flag;
    __shared__ unsigned short Ws[128 * 128];  // bf16 bits, 32 KB
    __shared__ float As[2 * 128];
    for (int i = threadIdx.x; i < 128 * 128; i += 256)
        Ws[i] = f32_to_bf16_raw(load_elem(W1, i, f));
    int rbase0 = blockIdx.x * G1_ROWS;
    for (int r = 0; r < G1_ROWS; r += 2) {
        __syncthreads();
        int rbase = rbase0 + r;
        {
            int i = threadIdx.x;
            int rr = rbase + (i >> 7);
            As[i] = (rr < N) ? load_elem(h, (size_t)rr * 128 + (i & 127), f) : 0.f;
        }
        __syncthreads();
        int row = rbase + (threadIdx.x >> 7);
        int col = threadIdx.x & 127;
        if (row < N) {
            const float* a = &As[(threadIdx.x >> 7) << 7];
            float acc = 0.f;
#pragma unroll
            for (int k = 0; k < 128; ++k)
                acc += a[k] * bf16_raw_to_f32(Ws[k * 128 + col]);
            feat1[(size_t)row * 128 + col] = f32_to_bf16_raw(acc);
        }
    }
}

// ---- GEMM2: feat2[N,64] (bf16) = elu(agg1[N,128]) @ W2[128,64] ----
#define G2_ROWS 64
__global__ void gemm2_kernel(const float* __restrict__ agg1,
                             const void* __restrict__ W2,
                             unsigned short* __restrict__ feat2, int N,
                             const int* __restrict__ flag) {
    const int f = *flag;
    __shared__ float Ws[128 * 64];
    __shared__ float As[4 * 128];
    for (int i = threadIdx.x; i < 128 * 64; i += 256)
        Ws[i] = load_elem(W2, i, f);
    int rbase0 = blockIdx.x * G2_ROWS;
    for (int r = 0; r < G2_ROWS; r += 4) {
        __syncthreads();
        int rbase = rbase0 + r;
        for (int i = threadIdx.x; i < 512; i += 256) {
            int rr = rbase + (i >> 7);
            float v = (rr < N) ? agg1[(size_t)rr * 128 + (i & 127)] : 0.f;
            As[i] = (v > 0.f) ? v : expm1f(v);   // ELU
        }
        __syncthreads();
        int row = rbase + (threadIdx.x >> 6);
        int col = threadIdx.x & 63;
        if (row < N) {
            const float* a = &As[(threadIdx.x >> 6) << 7];
            float acc = 0.f;
#pragma unroll
            for (int k = 0; k < 128; ++k)
                acc += a[k] * Ws[k * 64 + col];
            feat2[(size_t)row * 64 + col] = f32_to_bf16_raw(acc);
        }
    }
}

// ======= layer 1 fused GAT: one wave per dst, online softmax, 8-edge ILP ==
// Numerics bit-identical to R7: same edge order, same op sequence in the
// online update. Only the SCHEDULE changes (8 gathers + 8 shfl trees issued
// independently before the serial updates).
__global__ void gat1_kernel(const unsigned short* __restrict__ feat1,
                            const int* __restrict__ csr_src,
                            const int* __restrict__ start,
                            float* __restrict__ agg1, int N) {
    int wave = blockIdx.x * 4 + (threadIdx.x >> 6);
    if (wave >= N) return;
    int lane = threadIdx.x & 63;
    const unsigned* F = (const unsigned*)feat1;   // 2 bf16 per uint
    unsigned fdu = F[(size_t)wave * 64 + lane];
    float fdx = bf16_raw_to_f32((unsigned short)(fdu & 0xffffu));
    float fdy = bf16_raw_to_f32((unsigned short)(fdu >> 16));

    float m = -__builtin_inff(), l = 0.f, a0 = 0.f, a1 = 0.f;
    int e0 = start[wave], e1 = start[wave + 1];
    int idx = e0;
    for (; idx + 8 <= e1; idx += 8) {
        int sid[8];
#pragma unroll
        for (int j = 0; j < 8; ++j) sid[j] = csr_src[idx + j];
        unsigned fsu[8];
#pragma unroll
        for (int j = 0; j < 8; ++j) fsu[j] = F[(size_t)sid[j] * 64 + lane];
        float fx[8], fy[8], p[8];
#pragma unroll
        for (int j = 0; j < 8; ++j) {
            fx[j] = bf16_raw_to_f32((unsigned short)(fsu[j] & 0xffffu));
            fy[j] = bf16_raw_to_f32((unsigned short)(fsu[j] >> 16));
            p[j]  = fdx * fx[j] + fdy * fy[j];
        }
#pragma unroll
        for (int j = 0; j < 8; ++j) p[j] += __shfl_xor(p[j], 1);
#pragma unroll
        for (int j = 0; j < 8; ++j) p[j] += __shfl_xor(p[j], 2);
#pragma unroll
        for (int j = 0; j < 8; ++j) p[j] += __shfl_xor(p[j], 4);   // head dot
#pragma unroll
        for (int j = 0; j < 8; ++j) {
            float sc = p[j] * 0.25f;          // 16^-0.5
            float mn = fmaxf(m, sc);
            float sf = __expf(m - mn);
            float w  = __expf(sc - mn);
            a0 = a0 * sf + w * fx[j];
            a1 = a1 * sf + w * fy[j];
            l  = l  * sf + w;
            m  = mn;
        }
    }
    for (; idx < e1; ++idx) {                 // tail: R7's exact serial loop
        int s = csr_src[idx];
        unsigned fsu = F[(size_t)s * 64 + lane];
        float fx = bf16_raw_to_f32((unsigned short)(fsu & 0xffffu));
        float fy = bf16_raw_to_f32((unsigned short)(fsu >> 16));
        float p = fdx * fx + fdy * fy;
        p += __shfl_xor(p, 1);
        p += __shfl_xor(p, 2);
        p += __shfl_xor(p, 4);
        float sc = p * 0.25f;
        float mn = fmaxf(m, sc);
        float sf = __expf(m - mn);
        float w  = __expf(sc - mn);
        a0 = a0 * sf + w * fx;
        a1 = a1 * sf + w * fy;
        l  = l  * sf + w;
        m  = mn;
    }
    float rcp = 1.f / fmaxf(l, 1e-9f);
    float2 o; o.x = a0 * rcp; o.y = a1 * rcp;
    ((float2*)agg1)[(size_t)wave * 64 + lane] = o;
}

// ======= layer 2 fused GAT: one wave per dst, 1x64, 8-edge ILP ============
// Writes the final output directly (finalize folded in).
__global__ void gat2_kernel(const unsigned short* __restrict__ feat2,
                            const int* __restrict__ csr_src,
                            const int* __restrict__ start,
                            void* __restrict__ out, int N,
                            const int* __restrict__ flag) {
    int wave = blockIdx.x * 4 + (threadIdx.x >> 6);
    if (wave >= N) return;
    int lane = threadIdx.x & 63;
    const int f = *flag;
    float fd = bf16_raw_to_f32(feat2[(size_t)wave * 64 + lane]);

    float m = -__builtin_inff(), l = 0.f, a = 0.f;
    int e0 = start[wave], e1 = start[wave + 1];
    int idx = e0;
    for (; idx + 8 <= e1; idx += 8) {
        int sid[8];
#pragma unroll
        for (int j = 0; j < 8; ++j) sid[j] = csr_src[idx + j];
        float fs[8], p[8];
#pragma unroll
        for (int j = 0; j < 8; ++j) fs[j] = bf16_raw_to_f32(feat2[(size_t)sid[j] * 64 + lane]);
#pragma unroll
        for (int j = 0; j < 8; ++j) p[j] = fd * fs[j];
#pragma unroll
        for (int j = 0; j < 8; ++j) p[j] += __shfl_xor(p[j], 1);
#pragma unroll
        for (int j = 0; j < 8; ++j) p[j] += __shfl_xor(p[j], 2);
#pragma unroll
        for (int j = 0; j < 8; ++j) p[j] += __shfl_xor(p[j], 4);
#pragma unroll
        for (int j = 0; j < 8; ++j) p[j] += __shfl_xor(p[j], 8);
#pragma unroll
        for (int j = 0; j < 8; ++j) p[j] += __shfl_xor(p[j], 16);
#pragma unroll
        for (int j = 0; j < 8; ++j) p[j] += __shfl_xor(p[j], 32);  // full dot
#pragma unroll
        for (int j = 0; j < 8; ++j) {
            float sc = p[j] * 0.125f;         // 64^-0.5
            float mn = fmaxf(m, sc);
            float sf = __expf(m - mn);
            float w  = __expf(sc - mn);
            a = a * sf + w * fs[j];
            l = l * sf + w;
            m = mn;
        }
    }
    for (; idx < e1; ++idx) {                 // tail: R7's exact serial loop
        int s = csr_src[idx];
        float fs = bf16_raw_to_f32(feat2[(size_t)s * 64 + lane]);
        float p = fd * fs;
        p += __shfl_xor(p, 1);
        p += __shfl_xor(p, 2);
        p += __shfl_xor(p, 4);
        p += __shfl_xor(p, 8);
        p += __shfl_xor(p, 16);
        p += __shfl_xor(p, 32);
        float sc = p * 0.125f;
        float mn = fmaxf(m, sc);
        float sf = __expf(m - mn);
        float w  = __expf(sc - mn);
        a = a * sf + w * fs;
        l = l * sf + w;
        m = mn;
    }
    float rcp = 1.f / fmaxf(l, 1e-9f);
    float v = a * rcp;
    size_t o = (size_t)wave * 64 + lane;
    if (f) ((float*)out)[o] = v;
    else   ((unsigned short*)out)[o] = f32_to_bf16_raw(v);
}

extern "C" void kernel_launch(void* const* d_in, const int* in_sizes, int n_in,
                              void* d_out, int out_size, void* d_ws, size_t ws_size,
                              hipStream_t stream) {
    const void* h  = d_in[0];
    const void* W1 = d_in[1];
    const void* W2 = d_in[2];
    const int* src = (const int*)d_in[3];
    const int* dst = (const int*)d_in[4];

    float* ws = (float*)d_ws;
    // Layout (4-byte words), peak ~11.4M words = 45.3 MB:
    //   [0,     3.2M)   feat1 [N,128] bf16 (6.4M ushort)
    //   [3.2M,  9.6M)   agg1 [N,128] fp32
    //   [0,     1.6M)   feat2 [N,64] bf16  (reuses feat1 space after dead)
    //   [9.6M, 11.2M)   csr_src [E] int
    //   [11.2M,11.26M)  start [N+1] int
    //   [11.26M,11.32M) cursor/deg [N] int
    //   [11.33M]        dtype flag
    unsigned short* feat1 = (unsigned short*)ws;
    float* agg1           = ws + 3200000;
    unsigned short* feat2 = (unsigned short*)ws;      // after feat1 dead
    int*   csr_src        = (int*)(ws + 9600000);
    int*   start          = (int*)(ws + 11200000);
    int*   cursor         = (int*)(ws + 11260000);
    int*   flag           = (int*)(ws + 11330000);

    detect_dtype_kernel<<<1, 256, 0, stream>>>((const unsigned short*)W1, flag);

    // ---- CSR by dst (shared by both layers), storing src ids ----
    (void)hipMemsetAsync(cursor, 0, (size_t)N_NODES * 4, stream);
    count_kernel<<<N_EDGES / 256, 256, 0, stream>>>(dst, cursor, N_EDGES);
    scan_kernel<<<1, 1024, 0, stream>>>(cursor, start, cursor, N_NODES);
    fill_kernel<<<N_EDGES / 256, 256, 0, stream>>>(dst, src, start, cursor, csr_src, N_EDGES);

    gemm1_kernel<<<(N_NODES + G1_ROWS - 1) / G1_ROWS, 256, 0, stream>>>(h, W1, feat1, N_NODES, flag);
    gat1_kernel<<<(N_NODES + 3) / 4, 256, 0, stream>>>(feat1, csr_src, start, agg1, N_NODES);
    gemm2_kernel<<<(N_NODES + G2_ROWS - 1) / G2_ROWS, 256, 0, stream>>>(agg1, W2, feat2, N_NODES, flag);
    gat2_kernel<<<(N_NODES + 3) / 4, 256, 0, stream>>>(feat2, csr_src, start, d_out, N_NODES, flag);
}

// Round 9
// 575.956 us; speedup vs baseline: 31.4460x; 1.2704x over previous
//
#include <hip/hip_runtime.h>
#include <hip/hip_bf16.h>

#define N_NODES 50000
#define N_EDGES 1600000

typedef short bf16x8 __attribute__((ext_vector_type(8)));   // 8 bf16 = 4 VGPRs
typedef float f32x4  __attribute__((ext_vector_type(4)));   // MFMA accumulator

__device__ __forceinline__ float bf16_raw_to_f32(unsigned short u) {
    return __uint_as_float(((unsigned)u) << 16);
}
__device__ __forceinline__ unsigned short f32_to_bf16_raw(float v) {
    unsigned u = __float_as_uint(v);
    return (unsigned short)((u + 0x7fffu + ((u >> 16) & 1u)) >> 16);
}
// Load element i of a float tensor stored fp32 (f=1) or bf16 (f=0).
__device__ __forceinline__ float load_elem(const void* p, size_t i, int f) {
    if (f) return ((const float*)p)[i];
    return bf16_raw_to_f32(((const unsigned short*)p)[i]);
}

// ---- dtype probe: decode even 16-bit slots of W1 as bf16; fp32 storage
// shows |v| >> 1e4 with prob ~1. flag=1 -> fp32 storage. (verified R4)
__global__ void detect_dtype_kernel(const unsigned short* __restrict__ w1raw,
                                    int* __restrict__ flag) {
    __shared__ float red[256];
    float mx = 0.f;
    for (int i = threadIdx.x * 2; i < 16384; i += 512) {
        float v = fabsf(bf16_raw_to_f32(w1raw[i]));
        if (!isnan(v)) mx = fmaxf(mx, v);
    }
    red[threadIdx.x] = mx;
    __syncthreads();
    for (int s = 128; s > 0; s >>= 1) {
        if (threadIdx.x < s) red[threadIdx.x] = fmaxf(red[threadIdx.x], red[threadIdx.x + s]);
        __syncthreads();
    }
    if (threadIdx.x == 0) flag[0] = (red[0] > 1e4f) ? 1 : 0;
}

// ---- prep: W1T[n][k] (128x136 bf16) and W2T[n][k] (64x136 bf16), padded
// rows keep 16-B fragment alignment AND let MFMA B-frags load straight from
// global (L1/L2-resident, shared by all GEMM blocks -> no LDS staging).
#define WPAD 136
__global__ void prep_kernel(const void* __restrict__ W1, const void* __restrict__ W2,
                            unsigned short* __restrict__ W1T,
                            unsigned short* __restrict__ W2T,
                            const int* __restrict__ flag) {
    const int f = *flag;
    int bid = blockIdx.x, tid = threadIdx.x;
    if (bid < 8) {          // W1: 128 k x 128 n
        int n = bid * 16 + (tid & 15);
        int kb = (tid >> 4) * 8;
        for (int j = 0; j < 8; ++j)
            W1T[n * WPAD + kb + j] = f32_to_bf16_raw(load_elem(W1, (size_t)(kb + j) * 128 + n, f));
    } else {                // W2: 128 k x 64 n
        int n = (bid - 8) * 16 + (tid & 15);
        int kb = (tid >> 4) * 8;
        for (int j = 0; j < 8; ++j)
            W2T[n * WPAD + kb + j] = f32_to_bf16_raw(load_elem(W2, (size_t)(kb + j) * 64 + n, f));
    }
}

// ======================= CSR build (by dst) =======================
__global__ void count_kernel(const int* __restrict__ dst, int* __restrict__ cnt, int E) {
    int e = blockIdx.x * 256 + threadIdx.x;
    if (e < E) atomicAdd(cnt + dst[e], 1);
}

__global__ void scan_kernel(const int* __restrict__ deg, int* __restrict__ start,
                            int* __restrict__ cursor, int n) {
    __shared__ int part[1024];
    int t = threadIdx.x;
    int chunk = (n + 1023) / 1024;
    int lo = t * chunk, hi = min(lo + chunk, n);
    int s = 0;
    for (int i = lo; i < hi; ++i) s += deg[i];
    part[t] = s;
    __syncthreads();
    for (int off = 1; off < 1024; off <<= 1) {
        int v = (t >= off) ? part[t - off] : 0;
        __syncthreads();
        part[t] += v;
        __syncthreads();
    }
    int base = (t == 0) ? 0 : part[t - 1];
    for (int i = lo; i < hi; ++i) {
        start[i] = base;
        base += deg[i];
        cursor[i] = 0;
    }
    if (t == 1023) start[n] = part[1023];
}

__global__ void fill_kernel(const int* __restrict__ dst, const int* __restrict__ src,
                            const int* __restrict__ start,
                            int* __restrict__ cursor, int* __restrict__ csr_src, int E) {
    int e = blockIdx.x * 256 + threadIdx.x;
    if (e >= E) return;
    int d = dst[e];
    int p = atomicAdd(cursor + d, 1);
    csr_src[start[d] + p] = src[e];
}

// ---- MFMA GEMM1: feat1[N,128] (bf16) = h[N,128] @ W1 ----
// Block = 4 waves x 16 rows = 64 rows; wave does 8 col-tiles x 4 k-steps.
// A-frag: lane holds h[m=lane&15][k=(lane>>4)*8+j]; B-frag: W1T[n][k] same
// index pattern; C/D: col=lane&15, row=(lane>>4)*4+reg (gfx950-verified).
__global__ void gemm1_mfma_kernel(const void* __restrict__ h,
                                  const unsigned short* __restrict__ W1T,
                                  unsigned short* __restrict__ feat1, int N,
                                  const int* __restrict__ flag) {
    const int f = *flag;
    int lane = threadIdx.x & 63;
    int rbase = blockIdx.x * 64 + (threadIdx.x >> 6) * 16;
    int arow = rbase + (lane & 15);
    int arowc = min(arow, N - 1);
    int kb0 = (lane >> 4) * 8;

    f32x4 acc[8];
#pragma unroll
    for (int t = 0; t < 8; ++t) acc[t] = (f32x4){0.f, 0.f, 0.f, 0.f};

#pragma unroll
    for (int ks = 0; ks < 4; ++ks) {
        int kb = ks * 32 + kb0;
        bf16x8 afrag;
        if (f == 0) {
            afrag = *(const bf16x8*)((const unsigned short*)h + (size_t)arowc * 128 + kb);
        } else {
            const float* hp = (const float*)h + (size_t)arowc * 128 + kb;
#pragma unroll
            for (int j = 0; j < 8; ++j) afrag[j] = (short)f32_to_bf16_raw(hp[j]);
        }
#pragma unroll
        for (int t = 0; t < 8; ++t) {
            int n = t * 16 + (lane & 15);
            bf16x8 bfrag = *(const bf16x8*)(W1T + n * WPAD + kb);
            acc[t] = __builtin_amdgcn_mfma_f32_16x16x32_bf16(afrag, bfrag, acc[t], 0, 0, 0);
        }
    }
    int orow0 = rbase + (lane >> 4) * 4;
    int col = lane & 15;
#pragma unroll
    for (int t = 0; t < 8; ++t)
#pragma unroll
        for (int r = 0; r < 4; ++r) {
            int row = orow0 + r;
            if (row < N)
                feat1[(size_t)row * 128 + t * 16 + col] = f32_to_bf16_raw(acc[t][r]);
        }
}

// ---- MFMA GEMM2: feat2[N,64] (bf16) = agg1e[N,128] (bf16, ELU pre-applied
// by gat1 epilogue) @ W2 ----
__global__ void gemm2_mfma_kernel(const unsigned short* __restrict__ agg1e,
                                  const unsigned short* __restrict__ W2T,
                                  unsigned short* __restrict__ feat2, int N) {
    int lane = threadIdx.x & 63;
    int rbase = blockIdx.x * 64 + (threadIdx.x >> 6) * 16;
    int arow = rbase + (lane & 15);
    int arowc = min(arow, N - 1);
    int kb0 = (lane >> 4) * 8;

    f32x4 acc[4];
#pragma unroll
    for (int t = 0; t < 4; ++t) acc[t] = (f32x4){0.f, 0.f, 0.f, 0.f};

#pragma unroll
    for (int ks = 0; ks < 4; ++ks) {
        int kb = ks * 32 + kb0;
        bf16x8 afrag = *(const bf16x8*)(agg1e + (size_t)arowc * 128 + kb);
#pragma unroll
        for (int t = 0; t < 4; ++t) {
            int n = t * 16 + (lane & 15);
            bf16x8 bfrag = *(const bf16x8*)(W2T + n * WPAD + kb);
            acc[t] = __builtin_amdgcn_mfma_f32_16x16x32_bf16(afrag, bfrag, acc[t], 0, 0, 0);
        }
    }
    int orow0 = rbase + (lane >> 4) * 4;
    int col = lane & 15;
#pragma unroll
    for (int t = 0; t < 4; ++t)
#pragma unroll
        for (int r = 0; r < 4; ++r) {
            int row = orow0 + r;
            if (row < N)
                feat2[(size_t)row * 64 + t * 16 + col] = f32_to_bf16_raw(acc[t][r]);
        }
}

// ======= layer 1 fused GAT: one wave per dst, online softmax, 8-edge ILP ==
// Epilogue now applies ELU and stores bf16 (feeds gemm2's A-fragments).
__global__ void gat1_kernel(const unsigned short* __restrict__ feat1,
                            const int* __restrict__ csr_src,
                            const int* __restrict__ start,
                            unsigned short* __restrict__ agg1e, int N) {
    int wave = blockIdx.x * 4 + (threadIdx.x >> 6);
    if (wave >= N) return;
    int lane = threadIdx.x & 63;
    const unsigned* F = (const unsigned*)feat1;   // 2 bf16 per uint
    unsigned fdu = F[(size_t)wave * 64 + lane];
    float fdx = bf16_raw_to_f32((unsigned short)(fdu & 0xffffu));
    float fdy = bf16_raw_to_f32((unsigned short)(fdu >> 16));

    float m = -__builtin_inff(), l = 0.f, a0 = 0.f, a1 = 0.f;
    int e0 = start[wave], e1 = start[wave + 1];
    int idx = e0;
    for (; idx + 8 <= e1; idx += 8) {
        int sid[8];
#pragma unroll
        for (int j = 0; j < 8; ++j) sid[j] = csr_src[idx + j];
        unsigned fsu[8];
#pragma unroll
        for (int j = 0; j < 8; ++j) fsu[j] = F[(size_t)sid[j] * 64 + lane];
        float fx[8], fy[8], p[8];
#pragma unroll
        for (int j = 0; j < 8; ++j) {
            fx[j] = bf16_raw_to_f32((unsigned short)(fsu[j] & 0xffffu));
            fy[j] = bf16_raw_to_f32((unsigned short)(fsu[j] >> 16));
            p[j]  = fdx * fx[j] + fdy * fy[j];
        }
#pragma unroll
        for (int j = 0; j < 8; ++j) p[j] += __shfl_xor(p[j], 1);
#pragma unroll
        for (int j = 0; j < 8; ++j) p[j] += __shfl_xor(p[j], 2);
#pragma unroll
        for (int j = 0; j < 8; ++j) p[j] += __shfl_xor(p[j], 4);   // head dot
#pragma unroll
        for (int j = 0; j < 8; ++j) {
            float sc = p[j] * 0.25f;          // 16^-0.5
            float mn = fmaxf(m, sc);
            float sf = __expf(m - mn);
            float w  = __expf(sc - mn);
            a0 = a0 * sf + w * fx[j];
            a1 = a1 * sf + w * fy[j];
            l  = l  * sf + w;
            m  = mn;
        }
    }
    for (; idx < e1; ++idx) {                 // tail: serial loop
        int s = csr_src[idx];
        unsigned fsu = F[(size_t)s * 64 + lane];
        float fx = bf16_raw_to_f32((unsigned short)(fsu & 0xffffu));
        float fy = bf16_raw_to_f32((unsigned short)(fsu >> 16));
        float p = fdx * fx + fdy * fy;
        p += __shfl_xor(p, 1);
        p += __shfl_xor(p, 2);
        p += __shfl_xor(p, 4);
        float sc = p * 0.25f;
        float mn = fmaxf(m, sc);
        float sf = __expf(m - mn);
        float w  = __expf(sc - mn);
        a0 = a0 * sf + w * fx;
        a1 = a1 * sf + w * fy;
        l  = l  * sf + w;
        m  = mn;
    }
    float rcp = 1.f / fmaxf(l, 1e-9f);
    float v0 = a0 * rcp, v1 = a1 * rcp;
    v0 = (v0 > 0.f) ? v0 : expm1f(v0);        // ELU fused here
    v1 = (v1 > 0.f) ? v1 : expm1f(v1);
    unsigned pk = (unsigned)f32_to_bf16_raw(v0) | ((unsigned)f32_to_bf16_raw(v1) << 16);
    ((unsigned*)agg1e)[(size_t)wave * 64 + lane] = pk;
}

// ======= layer 2 fused GAT: one wave per dst, 1x64, 8-edge ILP ============
__global__ void gat2_kernel(const unsigned short* __restrict__ feat2,
                            const int* __restrict__ csr_src,
                            const int* __restrict__ start,
                            void* __restrict__ out, int N,
                            const int* __restrict__ flag) {
    int wave = blockIdx.x * 4 + (threadIdx.x >> 6);
    if (wave >= N) return;
    int lane = threadIdx.x & 63;
    const int f = *flag;
    float fd = bf16_raw_to_f32(feat2[(size_t)wave * 64 + lane]);

    float m = -__builtin_inff(), l = 0.f, a = 0.f;
    int e0 = start[wave], e1 = start[wave + 1];
    int idx = e0;
    for (; idx + 8 <= e1; idx += 8) {
        int sid[8];
#pragma unroll
        for (int j = 0; j < 8; ++j) sid[j] = csr_src[idx + j];
        float fs[8], p[8];
#pragma unroll
        for (int j = 0; j < 8; ++j) fs[j] = bf16_raw_to_f32(feat2[(size_t)sid[j] * 64 + lane]);
#pragma unroll
        for (int j = 0; j < 8; ++j) p[j] = fd * fs[j];
#pragma unroll
        for (int j = 0; j < 8; ++j) p[j] += __shfl_xor(p[j], 1);
#pragma unroll
        for (int j = 0; j < 8; ++j) p[j] += __shfl_xor(p[j], 2);
#pragma unroll
        for (int j = 0; j < 8; ++j) p[j] += __shfl_xor(p[j], 4);
#pragma unroll
        for (int j = 0; j < 8; ++j) p[j] += __shfl_xor(p[j], 8);
#pragma unroll
        for (int j = 0; j < 8; ++j) p[j] += __shfl_xor(p[j], 16);
#pragma unroll
        for (int j = 0; j < 8; ++j) p[j] += __shfl_xor(p[j], 32);  // full dot
#pragma unroll
        for (int j = 0; j < 8; ++j) {
            float sc = p[j] * 0.125f;         // 64^-0.5
            float mn = fmaxf(m, sc);
            float sf = __expf(m - mn);
            float w  = __expf(sc - mn);
            a = a * sf + w * fs[j];
            l = l * sf + w;
            m = mn;
        }
    }
    for (; idx < e1; ++idx) {                 // tail: serial loop
        int s = csr_src[idx];
        float fs = bf16_raw_to_f32(feat2[(size_t)s * 64 + lane]);
        float p = fd * fs;
        p += __shfl_xor(p, 1);
        p += __shfl_xor(p, 2);
        p += __shfl_xor(p, 4);
        p += __shfl_xor(p, 8);
        p += __shfl_xor(p, 16);
        p += __shfl_xor(p, 32);
        float sc = p * 0.125f;
        float mn = fmaxf(m, sc);
        float sf = __expf(m - mn);
        float w  = __expf(sc - mn);
        a = a * sf + w * fs;
        l = l * sf + w;
        m = mn;
    }
    float rcp = 1.f / fmaxf(l, 1e-9f);
    float v = a * rcp;
    size_t o = (size_t)wave * 64 + lane;
    if (f) ((float*)out)[o] = v;
    else   ((unsigned short*)out)[o] = f32_to_bf16_raw(v);
}

extern "C" void kernel_launch(void* const* d_in, const int* in_sizes, int n_in,
                              void* d_out, int out_size, void* d_ws, size_t ws_size,
                              hipStream_t stream) {
    const void* h  = d_in[0];
    const void* W1 = d_in[1];
    const void* W2 = d_in[2];
    const int* src = (const int*)d_in[3];
    const int* dst = (const int*)d_in[4];

    float* ws = (float*)d_ws;
    // Layout (4-byte words), peak ~11.37M words = 45.5 MB:
    //   [0,     3.2M)   feat1 [N,128] bf16       (later: feat2 [N,64] bf16)
    //   [3.2M,  4.8M)   agg1e [N,128] bf16 (ELU applied)
    //   [9.6M, 11.2M)   csr_src [E] int
    //   [11.2M,11.26M)  start [N+1] int
    //   [11.26M,11.32M) cursor/deg [N] int
    //   [11.33M]        dtype flag
    //   [11.34M,11.349M) W1T 128x136 bf16
    //   [11.35M,11.355M) W2T 64x136 bf16
    unsigned short* feat1 = (unsigned short*)ws;
    unsigned short* agg1e = (unsigned short*)(ws + 3200000);
    unsigned short* feat2 = (unsigned short*)ws;      // after feat1 dead
    int*   csr_src        = (int*)(ws + 9600000);
    int*   start          = (int*)(ws + 11200000);
    int*   cursor         = (int*)(ws + 11260000);
    int*   flag           = (int*)(ws + 11330000);
    unsigned short* W1T   = (unsigned short*)(ws + 11340000);
    unsigned short* W2T   = (unsigned short*)(ws + 11350000);

    detect_dtype_kernel<<<1, 256, 0, stream>>>((const unsigned short*)W1, flag);
    prep_kernel<<<12, 256, 0, stream>>>(W1, W2, W1T, W2T, flag);

    // ---- CSR by dst (shared by both layers), storing src ids ----
    (void)hipMemsetAsync(cursor, 0, (size_t)N_NODES * 4, stream);
    count_kernel<<<N_EDGES / 256, 256, 0, stream>>>(dst, cursor, N_EDGES);
    scan_kernel<<<1, 1024, 0, stream>>>(cursor, start, cursor, N_NODES);
    fill_kernel<<<N_EDGES / 256, 256, 0, stream>>>(dst, src, start, cursor, csr_src, N_EDGES);

    gemm1_mfma_kernel<<<(N_NODES + 63) / 64, 256, 0, stream>>>(h, W1T, feat1, N_NODES, flag);
    gat1_kernel<<<(N_NODES + 3) / 4, 256, 0, stream>>>(feat1, csr_src, start, agg1e, N_NODES);
    gemm2_mfma_kernel<<<(N_NODES + 63) / 64, 256, 0, stream>>>(agg1e, W2T, feat2, N_NODES);
    gat2_kernel<<<(N_NODES + 3) / 4, 256, 0, stream>>>(feat2, csr_src, start, d_out, N_NODES, flag);
}

// Round 10
// 498.436 us; speedup vs baseline: 36.3366x; 1.1555x over previous
//
#include <hip/hip_runtime.h>
#include <hip/hip_bf16.h>

#define N_NODES 50000
#define N_EDGES 1600000

typedef short bf16x8 __attribute__((ext_vector_type(8)));   // 8 bf16 = 4 VGPRs
typedef float f32x4  __attribute__((ext_vector_type(4)));   // MFMA accumulator

__device__ __forceinline__ float bf16_raw_to_f32(unsigned short u) {
    return __uint_as_float(((unsigned)u) << 16);
}
__device__ __forceinline__ unsigned short f32_to_bf16_raw(float v) {
    unsigned u = __float_as_uint(v);
    return (unsigned short)((u + 0x7fffu + ((u >> 16) & 1u)) >> 16);
}
// Load element i of a float tensor stored fp32 (f=1) or bf16 (f=0).
__device__ __forceinline__ float load_elem(const void* p, size_t i, int f) {
    if (f) return ((const float*)p)[i];
    return bf16_raw_to_f32(((const unsigned short*)p)[i]);
}
// Unpack 8 bf16 (as uint4) -> 8 fp32. Low ushort of each uint is the even elem.
__device__ __forceinline__ void unpack8(uint4 u, float* f) {
    f[0] = __uint_as_float(u.x << 16);
    f[1] = __uint_as_float(u.x & 0xffff0000u);
    f[2] = __uint_as_float(u.y << 16);
    f[3] = __uint_as_float(u.y & 0xffff0000u);
    f[4] = __uint_as_float(u.z << 16);
    f[5] = __uint_as_float(u.z & 0xffff0000u);
    f[6] = __uint_as_float(u.w << 16);
    f[7] = __uint_as_float(u.w & 0xffff0000u);
}

// ---- dtype probe: decode even 16-bit slots of W1 as bf16; fp32 storage
// shows |v| >> 1e4 with prob ~1. flag=1 -> fp32 storage. (verified R4)
__global__ void detect_dtype_kernel(const unsigned short* __restrict__ w1raw,
                                    int* __restrict__ flag) {
    __shared__ float red[256];
    float mx = 0.f;
    for (int i = threadIdx.x * 2; i < 16384; i += 512) {
        float v = fabsf(bf16_raw_to_f32(w1raw[i]));
        if (!isnan(v)) mx = fmaxf(mx, v);
    }
    red[threadIdx.x] = mx;
    __syncthreads();
    for (int s = 128; s > 0; s >>= 1) {
        if (threadIdx.x < s) red[threadIdx.x] = fmaxf(red[threadIdx.x], red[threadIdx.x + s]);
        __syncthreads();
    }
    if (threadIdx.x == 0) flag[0] = (red[0] > 1e4f) ? 1 : 0;
}

// ---- prep: W1T[n][k] (128x136 bf16), W2T[n][k] (64x136 bf16) ----
#define WPAD 136
__global__ void prep_kernel(const void* __restrict__ W1, const void* __restrict__ W2,
                            unsigned short* __restrict__ W1T,
                            unsigned short* __restrict__ W2T,
                            const int* __restrict__ flag) {
    const int f = *flag;
    int bid = blockIdx.x, tid = threadIdx.x;
    if (bid < 8) {          // W1: 128 k x 128 n
        int n = bid * 16 + (tid & 15);
        int kb = (tid >> 4) * 8;
        for (int j = 0; j < 8; ++j)
            W1T[n * WPAD + kb + j] = f32_to_bf16_raw(load_elem(W1, (size_t)(kb + j) * 128 + n, f));
    } else {                // W2: 128 k x 64 n
        int n = (bid - 8) * 16 + (tid & 15);
        int kb = (tid >> 4) * 8;
        for (int j = 0; j < 8; ++j)
            W2T[n * WPAD + kb + j] = f32_to_bf16_raw(load_elem(W2, (size_t)(kb + j) * 64 + n, f));
    }
}

// ======================= CSR build (by dst) =======================
__global__ void count_kernel(const int* __restrict__ dst, int* __restrict__ cnt, int E) {
    int e = blockIdx.x * 256 + threadIdx.x;
    if (e < E) atomicAdd(cnt + dst[e], 1);
}

__global__ void scan_kernel(const int* __restrict__ deg, int* __restrict__ start,
                            int* __restrict__ cursor, int n) {
    __shared__ int part[1024];
    int t = threadIdx.x;
    int chunk = (n + 1023) / 1024;
    int lo = t * chunk, hi = min(lo + chunk, n);
    int s = 0;
    for (int i = lo; i < hi; ++i) s += deg[i];
    part[t] = s;
    __syncthreads();
    for (int off = 1; off < 1024; off <<= 1) {
        int v = (t >= off) ? part[t - off] : 0;
        __syncthreads();
        part[t] += v;
        __syncthreads();
    }
    int base = (t == 0) ? 0 : part[t - 1];
    for (int i = lo; i < hi; ++i) {
        start[i] = base;
        base += deg[i];
        cursor[i] = 0;
    }
    if (t == 1023) start[n] = part[1023];
}

__global__ void fill_kernel(const int* __restrict__ dst, const int* __restrict__ src,
                            const int* __restrict__ start,
                            int* __restrict__ cursor, int* __restrict__ csr_src, int E) {
    int e = blockIdx.x * 256 + threadIdx.x;
    if (e >= E) return;
    int d = dst[e];
    int p = atomicAdd(cursor + d, 1);
    csr_src[start[d] + p] = src[e];
}

// ---- MFMA GEMM1: feat1[N,128] (bf16) = h[N,128] @ W1 ---- (R9-proven)
__global__ void gemm1_mfma_kernel(const void* __restrict__ h,
                                  const unsigned short* __restrict__ W1T,
                                  unsigned short* __restrict__ feat1, int N,
                                  const int* __restrict__ flag) {
    const int f = *flag;
    int lane = threadIdx.x & 63;
    int rbase = blockIdx.x * 64 + (threadIdx.x >> 6) * 16;
    int arow = rbase + (lane & 15);
    int arowc = min(arow, N - 1);
    int kb0 = (lane >> 4) * 8;

    f32x4 acc[8];
#pragma unroll
    for (int t = 0; t < 8; ++t) acc[t] = (f32x4){0.f, 0.f, 0.f, 0.f};

#pragma unroll
    for (int ks = 0; ks < 4; ++ks) {
        int kb = ks * 32 + kb0;
        bf16x8 afrag;
        if (f == 0) {
            afrag = *(const bf16x8*)((const unsigned short*)h + (size_t)arowc * 128 + kb);
        } else {
            const float* hp = (const float*)h + (size_t)arowc * 128 + kb;
#pragma unroll
            for (int j = 0; j < 8; ++j) afrag[j] = (short)f32_to_bf16_raw(hp[j]);
        }
#pragma unroll
        for (int t = 0; t < 8; ++t) {
            int n = t * 16 + (lane & 15);
            bf16x8 bfrag = *(const bf16x8*)(W1T + n * WPAD + kb);
            acc[t] = __builtin_amdgcn_mfma_f32_16x16x32_bf16(afrag, bfrag, acc[t], 0, 0, 0);
        }
    }
    int orow0 = rbase + (lane >> 4) * 4;
    int col = lane & 15;
#pragma unroll
    for (int t = 0; t < 8; ++t)
#pragma unroll
        for (int r = 0; r < 4; ++r) {
            int row = orow0 + r;
            if (row < N)
                feat1[(size_t)row * 128 + t * 16 + col] = f32_to_bf16_raw(acc[t][r]);
        }
}

// ---- MFMA GEMM2: feat2[N,64] (bf16) = agg1e[N,128] (bf16) @ W2 ----
__global__ void gemm2_mfma_kernel(const unsigned short* __restrict__ agg1e,
                                  const unsigned short* __restrict__ W2T,
                                  unsigned short* __restrict__ feat2, int N) {
    int lane = threadIdx.x & 63;
    int rbase = blockIdx.x * 64 + (threadIdx.x >> 6) * 16;
    int arow = rbase + (lane & 15);
    int arowc = min(arow, N - 1);
    int kb0 = (lane >> 4) * 8;

    f32x4 acc[4];
#pragma unroll
    for (int t = 0; t < 4; ++t) acc[t] = (f32x4){0.f, 0.f, 0.f, 0.f};

#pragma unroll
    for (int ks = 0; ks < 4; ++ks) {
        int kb = ks * 32 + kb0;
        bf16x8 afrag = *(const bf16x8*)(agg1e + (size_t)arowc * 128 + kb);
#pragma unroll
        for (int t = 0; t < 4; ++t) {
            int n = t * 16 + (lane & 15);
            bf16x8 bfrag = *(const bf16x8*)(W2T + n * WPAD + kb);
            acc[t] = __builtin_amdgcn_mfma_f32_16x16x32_bf16(afrag, bfrag, acc[t], 0, 0, 0);
        }
    }
    int orow0 = rbase + (lane >> 4) * 4;
    int col = lane & 15;
#pragma unroll
    for (int t = 0; t < 4; ++t)
#pragma unroll
        for (int r = 0; r < 4; ++r) {
            int row = orow0 + r;
            if (row < N)
                feat2[(size_t)row * 64 + t * 16 + col] = f32_to_bf16_raw(acc[t][r]);
        }
}

// ======= layer 1 fused GAT: wave = 1 dst; 4 groups x 16 lanes, 2 edges/grp
// in flight. Lane owns 8 dims (uint4 load); head = 2 lanes -> 1 shfl level.
// Per-lane softmax update runs on deg/4 edges; partial states merged at end.
__global__ void gat1_kernel(const unsigned short* __restrict__ feat1,
                            const int* __restrict__ csr_src,
                            const int* __restrict__ start,
                            unsigned short* __restrict__ agg1e, int N) {
    int wave = blockIdx.x * 4 + (threadIdx.x >> 6);
    if (wave >= N) return;
    int lane = threadIdx.x & 63;
    int grp = lane >> 4, gl = lane & 15;         // dims 8*gl..8*gl+7, head=gl>>1
    const uint4* F = (const uint4*)feat1;        // row = 16 uint4
    float fd[8]; unpack8(F[(size_t)wave * 16 + gl], fd);

    float m = -__builtin_inff(), l = 0.f, a[8];
#pragma unroll
    for (int j = 0; j < 8; ++j) a[j] = 0.f;

    int e0 = start[wave], e1 = start[wave + 1];
    int base = e0;
    for (; base + 8 <= e1; base += 8) {          // 8 edges: 2 per group
        int s0 = csr_src[base + grp];
        int s1 = csr_src[base + 4 + grp];
        uint4 u0 = F[(size_t)s0 * 16 + gl];
        uint4 u1 = F[(size_t)s1 * 16 + gl];
        float f0[8], f1[8];
        unpack8(u0, f0); unpack8(u1, f1);
        float p0 = 0.f, p1 = 0.f;
#pragma unroll
        for (int j = 0; j < 8; ++j) { p0 += fd[j] * f0[j]; p1 += fd[j] * f1[j]; }
        p0 += __shfl_xor(p0, 1);                 // 16-dim head dot
        p1 += __shfl_xor(p1, 1);
        {
            float sc = p0 * 0.25f;
            float mn = fmaxf(m, sc);
            float sf = __expf(m - mn), w = __expf(sc - mn);
#pragma unroll
            for (int j = 0; j < 8; ++j) a[j] = a[j] * sf + w * f0[j];
            l = l * sf + w; m = mn;
        }
        {
            float sc = p1 * 0.25f;
            float mn = fmaxf(m, sc);
            float sf = __expf(m - mn), w = __expf(sc - mn);
#pragma unroll
            for (int j = 0; j < 8; ++j) a[j] = a[j] * sf + w * f1[j];
            l = l * sf + w; m = mn;
        }
    }
    for (; base < e1; base += 4) {               // tail: up to 4 edges/step
        int ed = base + grp;
        bool act = ed < e1;                      // uniform within group
        int s = act ? csr_src[ed] : 0;
        uint4 u = F[(size_t)s * 16 + gl];
        float fv[8]; unpack8(u, fv);
        float p = 0.f;
#pragma unroll
        for (int j = 0; j < 8; ++j) p += fd[j] * fv[j];
        p += __shfl_xor(p, 1);
        if (act) {
            float sc = p * 0.25f;
            float mn = fmaxf(m, sc);
            float sf = __expf(m - mn), w = __expf(sc - mn);
#pragma unroll
            for (int j = 0; j < 8; ++j) a[j] = a[j] * sf + w * fv[j];
            l = l * sf + w; m = mn;
        }
    }
    // merge the 4 group-partial online-softmax states
#pragma unroll
    for (int off = 16; off <= 32; off <<= 1) {
        float mo = __shfl_xor(m, off), lo = __shfl_xor(l, off);
        float b[8];
#pragma unroll
        for (int j = 0; j < 8; ++j) b[j] = __shfl_xor(a[j], off);
        float mn = fmaxf(m, mo);
        float sA = (m == mn) ? 1.f : __expf(m - mn);    // guards -inf/-inf
        float sB = (mo == mn) ? 1.f : __expf(mo - mn);
#pragma unroll
        for (int j = 0; j < 8; ++j) a[j] = a[j] * sA + b[j] * sB;
        l = l * sA + lo * sB; m = mn;
    }
    if (grp == 0) {
        float rcp = 1.f / fmaxf(l, 1e-9f);
        float v[8];
#pragma unroll
        for (int j = 0; j < 8; ++j) {
            float x = a[j] * rcp;
            v[j] = (x > 0.f) ? x : expm1f(x);            // ELU fused
        }
        uint4 pk;
        pk.x = (unsigned)f32_to_bf16_raw(v[0]) | ((unsigned)f32_to_bf16_raw(v[1]) << 16);
        pk.y = (unsigned)f32_to_bf16_raw(v[2]) | ((unsigned)f32_to_bf16_raw(v[3]) << 16);
        pk.z = (unsigned)f32_to_bf16_raw(v[4]) | ((unsigned)f32_to_bf16_raw(v[5]) << 16);
        pk.w = (unsigned)f32_to_bf16_raw(v[6]) | ((unsigned)f32_to_bf16_raw(v[7]) << 16);
        *(uint4*)(agg1e + (size_t)wave * 128 + gl * 8) = pk;
    }
}

// ======= layer 2 fused GAT: wave = 1 dst; 8 groups x 8 lanes, 2 edges/grp
// in flight. Lane owns 8 dims; full 64-dim dot = 3 shfl levels in-group.
__global__ void gat2_kernel(const unsigned short* __restrict__ feat2,
                            const int* __restrict__ csr_src,
                            const int* __restrict__ start,
                            void* __restrict__ out, int N,
                            const int* __restrict__ flag) {
    int wave = blockIdx.x * 4 + (threadIdx.x >> 6);
    if (wave >= N) return;
    int lane = threadIdx.x & 63;
    int grp = lane >> 3, gl = lane & 7;          // dims 8*gl..8*gl+7
    const int f = *flag;
    const uint4* F = (const uint4*)feat2;        // row = 8 uint4
    float fd[8]; unpack8(F[(size_t)wave * 8 + gl], fd);

    float m = -__builtin_inff(), l = 0.f, a[8];
#pragma unroll
    for (int j = 0; j < 8; ++j) a[j] = 0.f;

    int e0 = start[wave], e1 = start[wave + 1];
    int base = e0;
    for (; base + 16 <= e1; base += 16) {        // 16 edges: 2 per group
        int s0 = csr_src[base + grp];
        int s1 = csr_src[base + 8 + grp];
        uint4 u0 = F[(size_t)s0 * 8 + gl];
        uint4 u1 = F[(size_t)s1 * 8 + gl];
        float f0[8], f1[8];
        unpack8(u0, f0); unpack8(u1, f1);
        float p0 = 0.f, p1 = 0.f;
#pragma unroll
        for (int j = 0; j < 8; ++j) { p0 += fd[j] * f0[j]; p1 += fd[j] * f1[j]; }
        p0 += __shfl_xor(p0, 1); p1 += __shfl_xor(p1, 1);
        p0 += __shfl_xor(p0, 2); p1 += __shfl_xor(p1, 2);
        p0 += __shfl_xor(p0, 4); p1 += __shfl_xor(p1, 4);   // full 64-dim dot
        {
            float sc = p0 * 0.125f;
            float mn = fmaxf(m, sc);
            float sf = __expf(m - mn), w = __expf(sc - mn);
#pragma unroll
            for (int j = 0; j < 8; ++j) a[j] = a[j] * sf + w * f0[j];
            l = l * sf + w; m = mn;
        }
        {
            float sc = p1 * 0.125f;
            float mn = fmaxf(m, sc);
            float sf = __expf(m - mn), w = __expf(sc - mn);
#pragma unroll
            for (int j = 0; j < 8; ++j) a[j] = a[j] * sf + w * f1[j];
            l = l * sf + w; m = mn;
        }
    }
    for (; base < e1; base += 8) {               // tail: up to 8 edges/step
        int ed = base + grp;
        bool act = ed < e1;                      // uniform within group
        int s = act ? csr_src[ed] : 0;
        uint4 u = F[(size_t)s * 8 + gl];
        float fv[8]; unpack8(u, fv);
        float p = 0.f;
#pragma unroll
        for (int j = 0; j < 8; ++j) p += fd[j] * fv[j];
        p += __shfl_xor(p, 1);
        p += __shfl_xor(p, 2);
        p += __shfl_xor(p, 4);
        if (act) {
            float sc = p * 0.125f;
            float mn = fmaxf(m, sc);
            float sf = __expf(m - mn), w = __expf(sc - mn);
#pragma unroll
            for (int j = 0; j < 8; ++j) a[j] = a[j] * sf + w * fv[j];
            l = l * sf + w; m = mn;
        }
    }
    // merge the 8 group-partial states
#pragma unroll
    for (int off = 8; off <= 32; off <<= 1) {
        float mo = __shfl_xor(m, off), lo = __shfl_xor(l, off);
        float b[8];
#pragma unroll
        for (int j = 0; j < 8; ++j) b[j] = __shfl_xor(a[j], off);
        float mn = fmaxf(m, mo);
        float sA = (m == mn) ? 1.f : __expf(m - mn);
        float sB = (mo == mn) ? 1.f : __expf(mo - mn);
#pragma unroll
        for (int j = 0; j < 8; ++j) a[j] = a[j] * sA + b[j] * sB;
        l = l * sA + lo * sB; m = mn;
    }
    if (grp == 0) {
        float rcp = 1.f / fmaxf(l, 1e-9f);
        float v[8];
#pragma unroll
        for (int j = 0; j < 8; ++j) v[j] = a[j] * rcp;
        if (f) {
            float* op = (float*)out + (size_t)wave * 64 + gl * 8;
            *(float4*)(op)     = (float4){v[0], v[1], v[2], v[3]};
            *(float4*)(op + 4) = (float4){v[4], v[5], v[6], v[7]};
        } else {
            uint4 pk;
            pk.x = (unsigned)f32_to_bf16_raw(v[0]) | ((unsigned)f32_to_bf16_raw(v[1]) << 16);
            pk.y = (unsigned)f32_to_bf16_raw(v[2]) | ((unsigned)f32_to_bf16_raw(v[3]) << 16);
            pk.z = (unsigned)f32_to_bf16_raw(v[4]) | ((unsigned)f32_to_bf16_raw(v[5]) << 16);
            pk.w = (unsigned)f32_to_bf16_raw(v[6]) | ((unsigned)f32_to_bf16_raw(v[7]) << 16);
            *(uint4*)((unsigned short*)out + (size_t)wave * 64 + gl * 8) = pk;
        }
    }
}

extern "C" void kernel_launch(void* const* d_in, const int* in_sizes, int n_in,
                              void* d_out, int out_size, void* d_ws, size_t ws_size,
                              hipStream_t stream) {
    const void* h  = d_in[0];
    const void* W1 = d_in[1];
    const void* W2 = d_in[2];
    const int* src = (const int*)d_in[3];
    const int* dst = (const int*)d_in[4];

    float* ws = (float*)d_ws;
    // Layout (4-byte words), peak ~11.36M words = 45.5 MB:
    //   [0,     3.2M)   feat1 [N,128] bf16       (later: feat2 [N,64] bf16)
    //   [3.2M,  4.8M)   agg1e [N,128] bf16 (ELU applied)
    //   [9.6M, 11.2M)   csr_src [E] int
    //   [11.2M,11.26M)  start [N+1] int
    //   [11.26M,11.32M) cursor/deg [N] int
    //   [11.33M]        dtype flag
    //   [11.34M,11.349M) W1T 128x136 bf16
    //   [11.35M,11.355M) W2T 64x136 bf16
    unsigned short* feat1 = (unsigned short*)ws;
    unsigned short* agg1e = (unsigned short*)(ws + 3200000);
    unsigned short* feat2 = (unsigned short*)ws;      // after feat1 dead
    int*   csr_src        = (int*)(ws + 9600000);
    int*   start          = (int*)(ws + 11200000);
    int*   cursor         = (int*)(ws + 11260000);
    int*   flag           = (int*)(ws + 11330000);
    unsigned short* W1T   = (unsigned short*)(ws + 11340000);
    unsigned short* W2T   = (unsigned short*)(ws + 11350000);

    detect_dtype_kernel<<<1, 256, 0, stream>>>((const unsigned short*)W1, flag);
    prep_kernel<<<12, 256, 0, stream>>>(W1, W2, W1T, W2T, flag);

    // ---- CSR by dst (shared by both layers), storing src ids ----
    (void)hipMemsetAsync(cursor, 0, (size_t)N_NODES * 4, stream);
    count_kernel<<<N_EDGES / 256, 256, 0, stream>>>(dst, cursor, N_EDGES);
    scan_kernel<<<1, 1024, 0, stream>>>(cursor, start, cursor, N_NODES);
    fill_kernel<<<N_EDGES / 256, 256, 0, stream>>>(dst, src, start, cursor, csr_src, N_EDGES);

    gemm1_mfma_kernel<<<(N_NODES + 63) / 64, 256, 0, stream>>>(h, W1T, feat1, N_NODES, flag);
    gat1_kernel<<<(N_NODES + 3) / 4, 256, 0, stream>>>(feat1, csr_src, start, agg1e, N_NODES);
    gemm2_mfma_kernel<<<(N_NODES + 63) / 64, 256, 0, stream>>>(agg1e, W2T, feat2, N_NODES);
    gat2_kernel<<<(N_NODES + 3) / 4, 256, 0, stream>>>(feat2, csr_src, start, d_out, N_NODES, flag);
}

// Round 11
// 400.723 us; speedup vs baseline: 45.1970x; 1.2438x over previous
//
#include <hip/hip_runtime.h>
#include <hip/hip_bf16.h>

#define N_NODES 50000
#define N_EDGES 1600000

typedef short bf16x8 __attribute__((ext_vector_type(8)));   // 8 bf16 = 4 VGPRs
typedef float f32x4  __attribute__((ext_vector_type(4)));   // MFMA accumulator

__device__ __forceinline__ float bf16_raw_to_f32(unsigned short u) {
    return __uint_as_float(((unsigned)u) << 16);
}
__device__ __forceinline__ unsigned short f32_to_bf16_raw(float v) {
    unsigned u = __float_as_uint(v);
    return (unsigned short)((u + 0x7fffu + ((u >> 16) & 1u)) >> 16);
}
// Load element i of a float tensor stored fp32 (f=1) or bf16 (f=0).
__device__ __forceinline__ float load_elem(const void* p, size_t i, int f) {
    if (f) return ((const float*)p)[i];
    return bf16_raw_to_f32(((const unsigned short*)p)[i]);
}
// Unpack 8 bf16 (as uint4) -> 8 fp32. Low ushort of each uint is the even elem.
__device__ __forceinline__ void unpack8(uint4 u, float* f) {
    f[0] = __uint_as_float(u.x << 16);
    f[1] = __uint_as_float(u.x & 0xffff0000u);
    f[2] = __uint_as_float(u.y << 16);
    f[3] = __uint_as_float(u.y & 0xffff0000u);
    f[4] = __uint_as_float(u.z << 16);
    f[5] = __uint_as_float(u.z & 0xffff0000u);
    f[6] = __uint_as_float(u.w << 16);
    f[7] = __uint_as_float(u.w & 0xffff0000u);
}

// ---- dtype probe: decode even 16-bit slots of W1 as bf16; fp32 storage
// shows |v| >> 1e4 with prob ~1. flag=1 -> fp32 storage. (verified R4)
__global__ void detect_dtype_kernel(const unsigned short* __restrict__ w1raw,
                                    int* __restrict__ flag) {
    __shared__ float red[256];
    float mx = 0.f;
    for (int i = threadIdx.x * 2; i < 16384; i += 512) {
        float v = fabsf(bf16_raw_to_f32(w1raw[i]));
        if (!isnan(v)) mx = fmaxf(mx, v);
    }
    red[threadIdx.x] = mx;
    __syncthreads();
    for (int s = 128; s > 0; s >>= 1) {
        if (threadIdx.x < s) red[threadIdx.x] = fmaxf(red[threadIdx.x], red[threadIdx.x + s]);
        __syncthreads();
    }
    if (threadIdx.x == 0) flag[0] = (red[0] > 1e4f) ? 1 : 0;
}

// ---- prep: W1T[n][k] (128x136 bf16), W2T[n][k] (64x136 bf16) ----
#define WPAD 136
__global__ void prep_kernel(const void* __restrict__ W1, const void* __restrict__ W2,
                            unsigned short* __restrict__ W1T,
                            unsigned short* __restrict__ W2T,
                            const int* __restrict__ flag) {
    const int f = *flag;
    int bid = blockIdx.x, tid = threadIdx.x;
    if (bid < 8) {          // W1: 128 k x 128 n
        int n = bid * 16 + (tid & 15);
        int kb = (tid >> 4) * 8;
        for (int j = 0; j < 8; ++j)
            W1T[n * WPAD + kb + j] = f32_to_bf16_raw(load_elem(W1, (size_t)(kb + j) * 128 + n, f));
    } else {                // W2: 128 k x 64 n
        int n = (bid - 8) * 16 + (tid & 15);
        int kb = (tid >> 4) * 8;
        for (int j = 0; j < 8; ++j)
            W2T[n * WPAD + kb + j] = f32_to_bf16_raw(load_elem(W2, (size_t)(kb + j) * 64 + n, f));
    }
}

// ======================= CSR build (by dst) =======================
__global__ void count_kernel(const int* __restrict__ dst, int* __restrict__ cnt, int E) {
    int e = blockIdx.x * 256 + threadIdx.x;
    if (e < E) atomicAdd(cnt + dst[e], 1);
}

// ---- hierarchical scan (replaces R10's 110-us single-block scan) ----
#define SCAN_NB ((N_NODES + 255) / 256)     // 196 blocks
__global__ void scan1_kernel(const int* __restrict__ deg, int* __restrict__ partials, int n) {
    __shared__ int red[256];
    int i = blockIdx.x * 256 + threadIdx.x;
    red[threadIdx.x] = (i < n) ? deg[i] : 0;
    __syncthreads();
    for (int s = 128; s > 0; s >>= 1) {
        if (threadIdx.x < s) red[threadIdx.x] += red[threadIdx.x + s];
        __syncthreads();
    }
    if (threadIdx.x == 0) partials[blockIdx.x] = red[0];
}

// One block: exclusive-scan the 196 partials in place; write start[n] = total.
__global__ void scan2_kernel(int* __restrict__ partials, int nb,
                             int* __restrict__ start, int n) {
    __shared__ int tmp[256];
    int t = threadIdx.x;
    int v = (t < nb) ? partials[t] : 0;
    tmp[t] = v;
    __syncthreads();
    for (int off = 1; off < 256; off <<= 1) {
        int x = (t >= off) ? tmp[t - off] : 0;
        __syncthreads();
        tmp[t] += x;
        __syncthreads();
    }
    if (t < nb) partials[t] = tmp[t] - v;    // exclusive
    if (t == 255) start[n] = tmp[255];       // grand total
}

// Per-block exclusive scan + block offset -> start[i]; zero cursor (== deg,
// safe: each element read by its own thread before being overwritten).
__global__ void scan3_kernel(const int* __restrict__ deg,
                             const int* __restrict__ partials,
                             int* __restrict__ start,
                             int* __restrict__ cursor, int n) {
    __shared__ int tmp[256];
    int i = blockIdx.x * 256 + threadIdx.x;
    int t = threadIdx.x;
    int v = (i < n) ? deg[i] : 0;
    tmp[t] = v;
    __syncthreads();
    for (int off = 1; off < 256; off <<= 1) {
        int x = (t >= off) ? tmp[t - off] : 0;
        __syncthreads();
        tmp[t] += x;
        __syncthreads();
    }
    if (i < n) {
        start[i] = partials[blockIdx.x] + tmp[t] - v;
        cursor[i] = 0;
    }
}

__global__ void fill_kernel(const int* __restrict__ dst, const int* __restrict__ src,
                            const int* __restrict__ start,
                            int* __restrict__ cursor, int* __restrict__ csr_src, int E) {
    int e = blockIdx.x * 256 + threadIdx.x;
    if (e >= E) return;
    int d = dst[e];
    int p = atomicAdd(cursor + d, 1);
    csr_src[start[d] + p] = src[e];
}

// ---- MFMA GEMM1: feat1[N,128] (bf16) = h[N,128] @ W1 ---- (R9-proven)
__global__ void gemm1_mfma_kernel(const void* __restrict__ h,
                                  const unsigned short* __restrict__ W1T,
                                  unsigned short* __restrict__ feat1, int N,
                                  const int* __restrict__ flag) {
    const int f = *flag;
    int lane = threadIdx.x & 63;
    int rbase = blockIdx.x * 64 + (threadIdx.x >> 6) * 16;
    int arow = rbase + (lane & 15);
    int arowc = min(arow, N - 1);
    int kb0 = (lane >> 4) * 8;

    f32x4 acc[8];
#pragma unroll
    for (int t = 0; t < 8; ++t) acc[t] = (f32x4){0.f, 0.f, 0.f, 0.f};

#pragma unroll
    for (int ks = 0; ks < 4; ++ks) {
        int kb = ks * 32 + kb0;
        bf16x8 afrag;
        if (f == 0) {
            afrag = *(const bf16x8*)((const unsigned short*)h + (size_t)arowc * 128 + kb);
        } else {
            const float* hp = (const float*)h + (size_t)arowc * 128 + kb;
#pragma unroll
            for (int j = 0; j < 8; ++j) afrag[j] = (short)f32_to_bf16_raw(hp[j]);
        }
#pragma unroll
        for (int t = 0; t < 8; ++t) {
            int n = t * 16 + (lane & 15);
            bf16x8 bfrag = *(const bf16x8*)(W1T + n * WPAD + kb);
            acc[t] = __builtin_amdgcn_mfma_f32_16x16x32_bf16(afrag, bfrag, acc[t], 0, 0, 0);
        }
    }
    int orow0 = rbase + (lane >> 4) * 4;
    int col = lane & 15;
#pragma unroll
    for (int t = 0; t < 8; ++t)
#pragma unroll
        for (int r = 0; r < 4; ++r) {
            int row = orow0 + r;
            if (row < N)
                feat1[(size_t)row * 128 + t * 16 + col] = f32_to_bf16_raw(acc[t][r]);
        }
}

// ---- MFMA GEMM2: feat2[N,64] (bf16) = agg1e[N,128] (bf16) @ W2 ----
__global__ void gemm2_mfma_kernel(const unsigned short* __restrict__ agg1e,
                                  const unsigned short* __restrict__ W2T,
                                  unsigned short* __restrict__ feat2, int N) {
    int lane = threadIdx.x & 63;
    int rbase = blockIdx.x * 64 + (threadIdx.x >> 6) * 16;
    int arow = rbase + (lane & 15);
    int arowc = min(arow, N - 1);
    int kb0 = (lane >> 4) * 8;

    f32x4 acc[4];
#pragma unroll
    for (int t = 0; t < 4; ++t) acc[t] = (f32x4){0.f, 0.f, 0.f, 0.f};

#pragma unroll
    for (int ks = 0; ks < 4; ++ks) {
        int kb = ks * 32 + kb0;
        bf16x8 afrag = *(const bf16x8*)(agg1e + (size_t)arowc * 128 + kb);
#pragma unroll
        for (int t = 0; t < 4; ++t) {
            int n = t * 16 + (lane & 15);
            bf16x8 bfrag = *(const bf16x8*)(W2T + n * WPAD + kb);
            acc[t] = __builtin_amdgcn_mfma_f32_16x16x32_bf16(afrag, bfrag, acc[t], 0, 0, 0);
        }
    }
    int orow0 = rbase + (lane >> 4) * 4;
    int col = lane & 15;
#pragma unroll
    for (int t = 0; t < 4; ++t)
#pragma unroll
        for (int r = 0; r < 4; ++r) {
            int row = orow0 + r;
            if (row < N)
                feat2[(size_t)row * 64 + t * 16 + col] = f32_to_bf16_raw(acc[t][r]);
        }
}

// ======= layer 1 fused GAT: wave = 1 dst; 4 groups x 16 lanes (R10-proven)
__global__ void gat1_kernel(const unsigned short* __restrict__ feat1,
                            const int* __restrict__ csr_src,
                            const int* __restrict__ start,
                            unsigned short* __restrict__ agg1e, int N) {
    int wave = blockIdx.x * 4 + (threadIdx.x >> 6);
    if (wave >= N) return;
    int lane = threadIdx.x & 63;
    int grp = lane >> 4, gl = lane & 15;         // dims 8*gl..8*gl+7, head=gl>>1
    const uint4* F = (const uint4*)feat1;        // row = 16 uint4
    float fd[8]; unpack8(F[(size_t)wave * 16 + gl], fd);

    float m = -__builtin_inff(), l = 0.f, a[8];
#pragma unroll
    for (int j = 0; j < 8; ++j) a[j] = 0.f;

    int e0 = start[wave], e1 = start[wave + 1];
    int base = e0;
    for (; base + 8 <= e1; base += 8) {          // 8 edges: 2 per group
        int s0 = csr_src[base + grp];
        int s1 = csr_src[base + 4 + grp];
        uint4 u0 = F[(size_t)s0 * 16 + gl];
        uint4 u1 = F[(size_t)s1 * 16 + gl];
        float f0[8], f1[8];
        unpack8(u0, f0); unpack8(u1, f1);
        float p0 = 0.f, p1 = 0.f;
#pragma unroll
        for (int j = 0; j < 8; ++j) { p0 += fd[j] * f0[j]; p1 += fd[j] * f1[j]; }
        p0 += __shfl_xor(p0, 1);                 // 16-dim head dot
        p1 += __shfl_xor(p1, 1);
        {
            float sc = p0 * 0.25f;
            float mn = fmaxf(m, sc);
            float sf = __expf(m - mn), w = __expf(sc - mn);
#pragma unroll
            for (int j = 0; j < 8; ++j) a[j] = a[j] * sf + w * f0[j];
            l = l * sf + w; m = mn;
        }
        {
            float sc = p1 * 0.25f;
            float mn = fmaxf(m, sc);
            float sf = __expf(m - mn), w = __expf(sc - mn);
#pragma unroll
            for (int j = 0; j < 8; ++j) a[j] = a[j] * sf + w * f1[j];
            l = l * sf + w; m = mn;
        }
    }
    for (; base < e1; base += 4) {               // tail: up to 4 edges/step
        int ed = base + grp;
        bool act = ed < e1;                      // uniform within group
        int s = act ? csr_src[ed] : 0;
        uint4 u = F[(size_t)s * 16 + gl];
        float fv[8]; unpack8(u, fv);
        float p = 0.f;
#pragma unroll
        for (int j = 0; j < 8; ++j) p += fd[j] * fv[j];
        p += __shfl_xor(p, 1);
        if (act) {
            float sc = p * 0.25f;
            float mn = fmaxf(m, sc);
            float sf = __expf(m - mn), w = __expf(sc - mn);
#pragma unroll
            for (int j = 0; j < 8; ++j) a[j] = a[j] * sf + w * fv[j];
            l = l * sf + w; m = mn;
        }
    }
    // merge the 4 group-partial online-softmax states
#pragma unroll
    for (int off = 16; off <= 32; off <<= 1) {
        float mo = __shfl_xor(m, off), lo = __shfl_xor(l, off);
        float b[8];
#pragma unroll
        for (int j = 0; j < 8; ++j) b[j] = __shfl_xor(a[j], off);
        float mn = fmaxf(m, mo);
        float sA = (m == mn) ? 1.f : __expf(m - mn);    // guards -inf/-inf
        float sB = (mo == mn) ? 1.f : __expf(mo - mn);
#pragma unroll
        for (int j = 0; j < 8; ++j) a[j] = a[j] * sA + b[j] * sB;
        l = l * sA + lo * sB; m = mn;
    }
    if (grp == 0) {
        float rcp = 1.f / fmaxf(l, 1e-9f);
        float v[8];
#pragma unroll
        for (int j = 0; j < 8; ++j) {
            float x = a[j] * rcp;
            v[j] = (x > 0.f) ? x : expm1f(x);            // ELU fused
        }
        uint4 pk;
        pk.x = (unsigned)f32_to_bf16_raw(v[0]) | ((unsigned)f32_to_bf16_raw(v[1]) << 16);
        pk.y = (unsigned)f32_to_bf16_raw(v[2]) | ((unsigned)f32_to_bf16_raw(v[3]) << 16);
        pk.z = (unsigned)f32_to_bf16_raw(v[4]) | ((unsigned)f32_to_bf16_raw(v[5]) << 16);
        pk.w = (unsigned)f32_to_bf16_raw(v[6]) | ((unsigned)f32_to_bf16_raw(v[7]) << 16);
        *(uint4*)(agg1e + (size_t)wave * 128 + gl * 8) = pk;
    }
}

// ======= layer 2 fused GAT: wave = 1 dst; 8 groups x 8 lanes (R10-proven)
__global__ void gat2_kernel(const unsigned short* __restrict__ feat2,
                            const int* __restrict__ csr_src,
                            const int* __restrict__ start,
                            void* __restrict__ out, int N,
                            const int* __restrict__ flag) {
    int wave = blockIdx.x * 4 + (threadIdx.x >> 6);
    if (wave >= N) return;
    int lane = threadIdx.x & 63;
    int grp = lane >> 3, gl = lane & 7;          // dims 8*gl..8*gl+7
    const int f = *flag;
    const uint4* F = (const uint4*)feat2;        // row = 8 uint4
    float fd[8]; unpack8(F[(size_t)wave * 8 + gl], fd);

    float m = -__builtin_inff(), l = 0.f, a[8];
#pragma unroll
    for (int j = 0; j < 8; ++j) a[j] = 0.f;

    int e0 = start[wave], e1 = start[wave + 1];
    int base = e0;
    for (; base + 16 <= e1; base += 16) {        // 16 edges: 2 per group
        int s0 = csr_src[base + grp];
        int s1 = csr_src[base + 8 + grp];
        uint4 u0 = F[(size_t)s0 * 8 + gl];
        uint4 u1 = F[(size_t)s1 * 8 + gl];
        float f0[8], f1[8];
        unpack8(u0, f0); unpack8(u1, f1);
        float p0 = 0.f, p1 = 0.f;
#pragma unroll
        for (int j = 0; j < 8; ++j) { p0 += fd[j] * f0[j]; p1 += fd[j] * f1[j]; }
        p0 += __shfl_xor(p0, 1); p1 += __shfl_xor(p1, 1);
        p0 += __shfl_xor(p0, 2); p1 += __shfl_xor(p1, 2);
        p0 += __shfl_xor(p0, 4); p1 += __shfl_xor(p1, 4);   // full 64-dim dot
        {
            float sc = p0 * 0.125f;
            float mn = fmaxf(m, sc);
            float sf = __expf(m - mn), w = __expf(sc - mn);
#pragma unroll
            for (int j = 0; j < 8; ++j) a[j] = a[j] * sf + w * f0[j];
            l = l * sf + w; m = mn;
        }
        {
            float sc = p1 * 0.125f;
            float mn = fmaxf(m, sc);
            float sf = __expf(m - mn), w = __expf(sc - mn);
#pragma unroll
            for (int j = 0; j < 8; ++j) a[j] = a[j] * sf + w * f1[j];
            l = l * sf + w; m = mn;
        }
    }
    for (; base < e1; base += 8) {               // tail: up to 8 edges/step
        int ed = base + grp;
        bool act = ed < e1;                      // uniform within group
        int s = act ? csr_src[ed] : 0;
        uint4 u = F[(size_t)s * 8 + gl];
        float fv[8]; unpack8(u, fv);
        float p = 0.f;
#pragma unroll
        for (int j = 0; j < 8; ++j) p += fd[j] * fv[j];
        p += __shfl_xor(p, 1);
        p += __shfl_xor(p, 2);
        p += __shfl_xor(p, 4);
        if (act) {
            float sc = p * 0.125f;
            float mn = fmaxf(m, sc);
            float sf = __expf(m - mn), w = __expf(sc - mn);
#pragma unroll
            for (int j = 0; j < 8; ++j) a[j] = a[j] * sf + w * fv[j];
            l = l * sf + w; m = mn;
        }
    }
    // merge the 8 group-partial states
#pragma unroll
    for (int off = 8; off <= 32; off <<= 1) {
        float mo = __shfl_xor(m, off), lo = __shfl_xor(l, off);
        float b[8];
#pragma unroll
        for (int j = 0; j < 8; ++j) b[j] = __shfl_xor(a[j], off);
        float mn = fmaxf(m, mo);
        float sA = (m == mn) ? 1.f : __expf(m - mn);
        float sB = (mo == mn) ? 1.f : __expf(mo - mn);
#pragma unroll
        for (int j = 0; j < 8; ++j) a[j] = a[j] * sA + b[j] * sB;
        l = l * sA + lo * sB; m = mn;
    }
    if (grp == 0) {
        float rcp = 1.f / fmaxf(l, 1e-9f);
        float v[8];
#pragma unroll
        for (int j = 0; j < 8; ++j) v[j] = a[j] * rcp;
        if (f) {
            float* op = (float*)out + (size_t)wave * 64 + gl * 8;
            *(float4*)(op)     = (float4){v[0], v[1], v[2], v[3]};
            *(float4*)(op + 4) = (float4){v[4], v[5], v[6], v[7]};
        } else {
            uint4 pk;
            pk.x = (unsigned)f32_to_bf16_raw(v[0]) | ((unsigned)f32_to_bf16_raw(v[1]) << 16);
            pk.y = (unsigned)f32_to_bf16_raw(v[2]) | ((unsigned)f32_to_bf16_raw(v[3]) << 16);
            pk.z = (unsigned)f32_to_bf16_raw(v[4]) | ((unsigned)f32_to_bf16_raw(v[5]) << 16);
            pk.w = (unsigned)f32_to_bf16_raw(v[6]) | ((unsigned)f32_to_bf16_raw(v[7]) << 16);
            *(uint4*)((unsigned short*)out + (size_t)wave * 64 + gl * 8) = pk;
        }
    }
}

extern "C" void kernel_launch(void* const* d_in, const int* in_sizes, int n_in,
                              void* d_out, int out_size, void* d_ws, size_t ws_size,
                              hipStream_t stream) {
    const void* h  = d_in[0];
    const void* W1 = d_in[1];
    const void* W2 = d_in[2];
    const int* src = (const int*)d_in[3];
    const int* dst = (const int*)d_in[4];

    float* ws = (float*)d_ws;
    // Layout (4-byte words), peak ~11.36M words = 45.5 MB:
    //   [0,     3.2M)   feat1 [N,128] bf16       (later: feat2 [N,64] bf16)
    //   [3.2M,  4.8M)   agg1e [N,128] bf16 (ELU applied)
    //   [9.6M, 11.2M)   csr_src [E] int
    //   [11.2M,11.26M)  start [N+1] int
    //   [11.26M,11.32M) cursor/deg [N] int
    //   [11.33M]        dtype flag
    //   [11.331M,11.3315M) partials [196] int
    //   [11.34M,11.349M) W1T 128x136 bf16
    //   [11.35M,11.355M) W2T 64x136 bf16
    unsigned short* feat1 = (unsigned short*)ws;
    unsigned short* agg1e = (unsigned short*)(ws + 3200000);
    unsigned short* feat2 = (unsigned short*)ws;      // after feat1 dead
    int*   csr_src        = (int*)(ws + 9600000);
    int*   start          = (int*)(ws + 11200000);
    int*   cursor         = (int*)(ws + 11260000);
    int*   flag           = (int*)(ws + 11330000);
    int*   partials       = (int*)(ws + 11331000);
    unsigned short* W1T   = (unsigned short*)(ws + 11340000);
    unsigned short* W2T   = (unsigned short*)(ws + 11350000);

    detect_dtype_kernel<<<1, 256, 0, stream>>>((const unsigned short*)W1, flag);
    prep_kernel<<<12, 256, 0, stream>>>(W1, W2, W1T, W2T, flag);

    // ---- CSR by dst (shared by both layers), storing src ids ----
    (void)hipMemsetAsync(cursor, 0, (size_t)N_NODES * 4, stream);
    count_kernel<<<N_EDGES / 256, 256, 0, stream>>>(dst, cursor, N_EDGES);
    scan1_kernel<<<SCAN_NB, 256, 0, stream>>>(cursor, partials, N_NODES);
    scan2_kernel<<<1, 256, 0, stream>>>(partials, SCAN_NB, start, N_NODES);
    scan3_kernel<<<SCAN_NB, 256, 0, stream>>>(cursor, partials, start, cursor, N_NODES);
    fill_kernel<<<N_EDGES / 256, 256, 0, stream>>>(dst, src, start, cursor, csr_src, N_EDGES);

    gemm1_mfma_kernel<<<(N_NODES + 63) / 64, 256, 0, stream>>>(h, W1T, feat1, N_NODES, flag);
    gat1_kernel<<<(N_NODES + 3) / 4, 256, 0, stream>>>(feat1, csr_src, start, agg1e, N_NODES);
    gemm2_mfma_kernel<<<(N_NODES + 63) / 64, 256, 0, stream>>>(agg1e, W2T, feat2, N_NODES);
    gat2_kernel<<<(N_NODES + 3) / 4, 256, 0, stream>>>(feat2, csr_src, start, d_out, N_NODES, flag);
}

// Round 12
// 300.467 us; speedup vs baseline: 60.2777x; 1.3337x over previous
//
#include <hip/hip_runtime.h>
#include <hip/hip_bf16.h>

#define N_NODES 50000
#define N_EDGES 1600000
#define NBUCK 98              // ceil(50000/512) buckets of 512 nodes
#define EPB 4096              // edges per binning block
#define NB_A ((N_EDGES + EPB - 1) / EPB)   // 391

typedef short bf16x8 __attribute__((ext_vector_type(8)));
typedef float f32x4  __attribute__((ext_vector_type(4)));

__device__ __forceinline__ float bf16_raw_to_f32(unsigned short u) {
    return __uint_as_float(((unsigned)u) << 16);
}
__device__ __forceinline__ unsigned short f32_to_bf16_raw(float v) {
    unsigned u = __float_as_uint(v);
    return (unsigned short)((u + 0x7fffu + ((u >> 16) & 1u)) >> 16);
}
__device__ __forceinline__ float load_elem(const void* p, size_t i, int f) {
    if (f) return ((const float*)p)[i];
    return bf16_raw_to_f32(((const unsigned short*)p)[i]);
}
__device__ __forceinline__ void unpack8(uint4 u, float* f) {
    f[0] = __uint_as_float(u.x << 16);
    f[1] = __uint_as_float(u.x & 0xffff0000u);
    f[2] = __uint_as_float(u.y << 16);
    f[3] = __uint_as_float(u.y & 0xffff0000u);
    f[4] = __uint_as_float(u.z << 16);
    f[5] = __uint_as_float(u.z & 0xffff0000u);
    f[6] = __uint_as_float(u.w << 16);
    f[7] = __uint_as_float(u.w & 0xffff0000u);
}

// ---- dtype probe (verified R4): flag=1 -> fp32 storage ----
__global__ void detect_dtype_kernel(const unsigned short* __restrict__ w1raw,
                                    int* __restrict__ flag) {
    __shared__ float red[256];
    float mx = 0.f;
    for (int i = threadIdx.x * 2; i < 16384; i += 512) {
        float v = fabsf(bf16_raw_to_f32(w1raw[i]));
        if (!isnan(v)) mx = fmaxf(mx, v);
    }
    red[threadIdx.x] = mx;
    __syncthreads();
    for (int s = 128; s > 0; s >>= 1) {
        if (threadIdx.x < s) red[threadIdx.x] = fmaxf(red[threadIdx.x], red[threadIdx.x + s]);
        __syncthreads();
    }
    if (threadIdx.x == 0) flag[0] = (red[0] > 1e4f) ? 1 : 0;
}

// ---- prep: W1T[n][k] (128x136 bf16), W2T[n][k] (64x136 bf16) ----
#define WPAD 136
__global__ void prep_kernel(const void* __restrict__ W1, const void* __restrict__ W2,
                            unsigned short* __restrict__ W1T,
                            unsigned short* __restrict__ W2T,
                            const int* __restrict__ flag) {
    const int f = *flag;
    int bid = blockIdx.x, tid = threadIdx.x;
    if (bid < 8) {
        int n = bid * 16 + (tid & 15);
        int kb = (tid >> 4) * 8;
        for (int j = 0; j < 8; ++j)
            W1T[n * WPAD + kb + j] = f32_to_bf16_raw(load_elem(W1, (size_t)(kb + j) * 128 + n, f));
    } else {
        int n = (bid - 8) * 16 + (tid & 15);
        int kb = (tid >> 4) * 8;
        for (int j = 0; j < 8; ++j)
            W2T[n * WPAD + kb + j] = f32_to_bf16_raw(load_elem(W2, (size_t)(kb + j) * 64 + n, f));
    }
}

// ============ binned CSR build (kills fill's 16x write-amp) ============
// Stage 0: per-bucket edge counts (LDS histogram -> 98 global counters).
__global__ void bucket_count_kernel(const int* __restrict__ dst,
                                    int* __restrict__ bcnt, int E) {
    __shared__ int hist[NBUCK];
    int t = threadIdx.x;
    if (t < NBUCK) hist[t] = 0;
    __syncthreads();
    int e0 = blockIdx.x * EPB;
    for (int k = 0; k < 16; ++k) {
        int e = e0 + k * 256 + t;
        if (e < E) atomicAdd(&hist[dst[e] >> 9], 1);
    }
    __syncthreads();
    if (t < NBUCK && hist[t]) atomicAdd(&bcnt[t], hist[t]);
}

// Stage 1: scan 98 bucket counts -> bbase[99]; init bucket cursors.
__global__ void bucket_scan_kernel(const int* __restrict__ bcnt,
                                   int* __restrict__ bbase, int* __restrict__ bcur) {
    __shared__ int tmp[128];
    int t = threadIdx.x;
    int v = (t < NBUCK) ? bcnt[t] : 0;
    tmp[t] = v;
    __syncthreads();
    for (int off = 1; off < 128; off <<= 1) {
        int x = (t >= off) ? tmp[t - off] : 0;
        __syncthreads();
        tmp[t] += x;
        __syncthreads();
    }
    if (t < NBUCK) { int ex = tmp[t] - v; bbase[t] = ex; bcur[t] = ex; }
    if (t == NBUCK - 1) bbase[NBUCK] = tmp[t];
}

// Stage 2: scatter edges into bucket-contiguous intermediate array.
// Packed: low 16 bits = src (N<65536), bits 16..24 = dst & 511.
__global__ void binA_kernel(const int* __restrict__ src, const int* __restrict__ dst,
                            int* __restrict__ bcur, unsigned* __restrict__ inter, int E) {
    __shared__ int hist[NBUCK], gbase[NBUCK], cur[NBUCK];
    int t = threadIdx.x;
    if (t < NBUCK) hist[t] = 0;
    __syncthreads();
    int e0 = blockIdx.x * EPB;
    for (int k = 0; k < 16; ++k) {
        int e = e0 + k * 256 + t;
        if (e < E) atomicAdd(&hist[dst[e] >> 9], 1);
    }
    __syncthreads();
    if (t < NBUCK) {
        int hv = hist[t];
        gbase[t] = hv ? atomicAdd(&bcur[t], hv) : 0;
        cur[t] = 0;
    }
    __syncthreads();
    for (int k = 0; k < 16; ++k) {
        int e = e0 + k * 256 + t;
        if (e < E) {
            int d = dst[e];
            int b = d >> 9;
            int off = atomicAdd(&cur[b], 1);
            inter[gbase[b] + off] = (unsigned)src[e] | ((unsigned)(d & 511) << 16);
        }
    }
}

// Stage 3: one block per bucket. LDS per-node histogram + scan -> writes
// start[] (replaces count+scan kernels) and scatters csr_src within the
// bucket's L2-resident region (full-line writebacks).
__global__ void binB_kernel(const unsigned* __restrict__ inter,
                            const int* __restrict__ bbase,
                            int* __restrict__ csr_src, int* __restrict__ start,
                            int N, int E) {
    int b = blockIdx.x;
    int node0 = b << 9;
    int lo = bbase[b], hi = bbase[b + 1];
    __shared__ int hist[512];
    __shared__ int t2[256];
    int t = threadIdx.x;
    hist[t] = 0; hist[t + 256] = 0;
    __syncthreads();
    for (int e = lo + t; e < hi; e += 256) atomicAdd(&hist[inter[e] >> 16], 1);
    __syncthreads();
    int s0 = hist[2 * t], s1 = hist[2 * t + 1];
    t2[t] = s0 + s1;
    __syncthreads();
    for (int off = 1; off < 256; off <<= 1) {
        int x = (t >= off) ? t2[t - off] : 0;
        __syncthreads();
        t2[t] += x;
        __syncthreads();
    }
    int base = (t == 0) ? 0 : t2[t - 1];
    hist[2 * t] = base;
    hist[2 * t + 1] = base + s0;      // exclusive per-node prefixes
    __syncthreads();
    int nodeCnt = min(512, N - node0);
    for (int i = t; i < nodeCnt; i += 256) start[node0 + i] = lo + hist[i];
    if (b == NBUCK - 1 && t == 0) start[N] = E;
    __syncthreads();                   // hist becomes per-node cursors
    for (int e = lo + t; e < hi; e += 256) {
        unsigned u = inter[e];
        int slot = lo + atomicAdd(&hist[u >> 16], 1);
        csr_src[slot] = (int)(u & 0xffffu);
    }
}

// ---- MFMA GEMM1: feat1[N,128] (bf16) = h[N,128] @ W1 ---- (R9-proven)
__global__ void gemm1_mfma_kernel(const void* __restrict__ h,
                                  const unsigned short* __restrict__ W1T,
                                  unsigned short* __restrict__ feat1, int N,
                                  const int* __restrict__ flag) {
    const int f = *flag;
    int lane = threadIdx.x & 63;
    int rbase = blockIdx.x * 64 + (threadIdx.x >> 6) * 16;
    int arow = rbase + (lane & 15);
    int arowc = min(arow, N - 1);
    int kb0 = (lane >> 4) * 8;

    f32x4 acc[8];
#pragma unroll
    for (int t = 0; t < 8; ++t) acc[t] = (f32x4){0.f, 0.f, 0.f, 0.f};

#pragma unroll
    for (int ks = 0; ks < 4; ++ks) {
        int kb = ks * 32 + kb0;
        bf16x8 afrag;
        if (f == 0) {
            afrag = *(const bf16x8*)((const unsigned short*)h + (size_t)arowc * 128 + kb);
        } else {
            const float* hp = (const float*)h + (size_t)arowc * 128 + kb;
#pragma unroll
            for (int j = 0; j < 8; ++j) afrag[j] = (short)f32_to_bf16_raw(hp[j]);
        }
#pragma unroll
        for (int t = 0; t < 8; ++t) {
            int n = t * 16 + (lane & 15);
            bf16x8 bfrag = *(const bf16x8*)(W1T + n * WPAD + kb);
            acc[t] = __builtin_amdgcn_mfma_f32_16x16x32_bf16(afrag, bfrag, acc[t], 0, 0, 0);
        }
    }
    int orow0 = rbase + (lane >> 4) * 4;
    int col = lane & 15;
#pragma unroll
    for (int t = 0; t < 8; ++t)
#pragma unroll
        for (int r = 0; r < 4; ++r) {
            int row = orow0 + r;
            if (row < N)
                feat1[(size_t)row * 128 + t * 16 + col] = f32_to_bf16_raw(acc[t][r]);
        }
}

// ---- MFMA GEMM2: feat2[N,64] (bf16) = agg1e[N,128] (bf16) @ W2 ----
__global__ void gemm2_mfma_kernel(const unsigned short* __restrict__ agg1e,
                                  const unsigned short* __restrict__ W2T,
                                  unsigned short* __restrict__ feat2, int N) {
    int lane = threadIdx.x & 63;
    int rbase = blockIdx.x * 64 + (threadIdx.x >> 6) * 16;
    int arow = rbase + (lane & 15);
    int arowc = min(arow, N - 1);
    int kb0 = (lane >> 4) * 8;

    f32x4 acc[4];
#pragma unroll
    for (int t = 0; t < 4; ++t) acc[t] = (f32x4){0.f, 0.f, 0.f, 0.f};

#pragma unroll
    for (int ks = 0; ks < 4; ++ks) {
        int kb = ks * 32 + kb0;
        bf16x8 afrag = *(const bf16x8*)(agg1e + (size_t)arowc * 128 + kb);
#pragma unroll
        for (int t = 0; t < 4; ++t) {
            int n = t * 16 + (lane & 15);
            bf16x8 bfrag = *(const bf16x8*)(W2T + n * WPAD + kb);
            acc[t] = __builtin_amdgcn_mfma_f32_16x16x32_bf16(afrag, bfrag, acc[t], 0, 0, 0);
        }
    }
    int orow0 = rbase + (lane >> 4) * 4;
    int col = lane & 15;
#pragma unroll
    for (int t = 0; t < 4; ++t)
#pragma unroll
        for (int r = 0; r < 4; ++r) {
            int row = orow0 + r;
            if (row < N)
                feat2[(size_t)row * 64 + t * 16 + col] = f32_to_bf16_raw(acc[t][r]);
        }
}

// ======= layer 1 fused GAT: wave = 1 dst; 4 groups x 16 lanes (R10-proven)
__global__ void gat1_kernel(const unsigned short* __restrict__ feat1,
                            const int* __restrict__ csr_src,
                            const int* __restrict__ start,
                            unsigned short* __restrict__ agg1e, int N) {
    int wave = blockIdx.x * 4 + (threadIdx.x >> 6);
    if (wave >= N) return;
    int lane = threadIdx.x & 63;
    int grp = lane >> 4, gl = lane & 15;
    const uint4* F = (const uint4*)feat1;
    float fd[8]; unpack8(F[(size_t)wave * 16 + gl], fd);

    float m = -__builtin_inff(), l = 0.f, a[8];
#pragma unroll
    for (int j = 0; j < 8; ++j) a[j] = 0.f;

    int e0 = start[wave], e1 = start[wave + 1];
    int base = e0;
    for (; base + 8 <= e1; base += 8) {
        int s0 = csr_src[base + grp];
        int s1 = csr_src[base + 4 + grp];
        uint4 u0 = F[(size_t)s0 * 16 + gl];
        uint4 u1 = F[(size_t)s1 * 16 + gl];
        float f0[8], f1[8];
        unpack8(u0, f0); unpack8(u1, f1);
        float p0 = 0.f, p1 = 0.f;
#pragma unroll
        for (int j = 0; j < 8; ++j) { p0 += fd[j] * f0[j]; p1 += fd[j] * f1[j]; }
        p0 += __shfl_xor(p0, 1);
        p1 += __shfl_xor(p1, 1);
        {
            float sc = p0 * 0.25f;
            float mn = fmaxf(m, sc);
            float sf = __expf(m - mn), w = __expf(sc - mn);
#pragma unroll
            for (int j = 0; j < 8; ++j) a[j] = a[j] * sf + w * f0[j];
            l = l * sf + w; m = mn;
        }
        {
            float sc = p1 * 0.25f;
            float mn = fmaxf(m, sc);
            float sf = __expf(m - mn), w = __expf(sc - mn);
#pragma unroll
            for (int j = 0; j < 8; ++j) a[j] = a[j] * sf + w * f1[j];
            l = l * sf + w; m = mn;
        }
    }
    for (; base < e1; base += 4) {
        int ed = base + grp;
        bool act = ed < e1;
        int s = act ? csr_src[ed] : 0;
        uint4 u = F[(size_t)s * 16 + gl];
        float fv[8]; unpack8(u, fv);
        float p = 0.f;
#pragma unroll
        for (int j = 0; j < 8; ++j) p += fd[j] * fv[j];
        p += __shfl_xor(p, 1);
        if (act) {
            float sc = p * 0.25f;
            float mn = fmaxf(m, sc);
            float sf = __expf(m - mn), w = __expf(sc - mn);
#pragma unroll
            for (int j = 0; j < 8; ++j) a[j] = a[j] * sf + w * fv[j];
            l = l * sf + w; m = mn;
        }
    }
#pragma unroll
    for (int off = 16; off <= 32; off <<= 1) {
        float mo = __shfl_xor(m, off), lo = __shfl_xor(l, off);
        float bfr[8];
#pragma unroll
        for (int j = 0; j < 8; ++j) bfr[j] = __shfl_xor(a[j], off);
        float mn = fmaxf(m, mo);
        float sA = (m == mn) ? 1.f : __expf(m - mn);
        float sB = (mo == mn) ? 1.f : __expf(mo - mn);
#pragma unroll
        for (int j = 0; j < 8; ++j) a[j] = a[j] * sA + bfr[j] * sB;
        l = l * sA + lo * sB; m = mn;
    }
    if (grp == 0) {
        float rcp = 1.f / fmaxf(l, 1e-9f);
        float v[8];
#pragma unroll
        for (int j = 0; j < 8; ++j) {
            float x = a[j] * rcp;
            v[j] = (x > 0.f) ? x : expm1f(x);
        }
        uint4 pk;
        pk.x = (unsigned)f32_to_bf16_raw(v[0]) | ((unsigned)f32_to_bf16_raw(v[1]) << 16);
        pk.y = (unsigned)f32_to_bf16_raw(v[2]) | ((unsigned)f32_to_bf16_raw(v[3]) << 16);
        pk.z = (unsigned)f32_to_bf16_raw(v[4]) | ((unsigned)f32_to_bf16_raw(v[5]) << 16);
        pk.w = (unsigned)f32_to_bf16_raw(v[6]) | ((unsigned)f32_to_bf16_raw(v[7]) << 16);
        *(uint4*)(agg1e + (size_t)wave * 128 + gl * 8) = pk;
    }
}

// ======= layer 2 fused GAT: wave = 1 dst; 8 groups x 8 lanes (R10-proven)
__global__ void gat2_kernel(const unsigned short* __restrict__ feat2,
                            const int* __restrict__ csr_src,
                            const int* __restrict__ start,
                            void* __restrict__ out, int N,
                            const int* __restrict__ flag) {
    int wave = blockIdx.x * 4 + (threadIdx.x >> 6);
    if (wave >= N) return;
    int lane = threadIdx.x & 63;
    int grp = lane >> 3, gl = lane & 7;
    const int f = *flag;
    const uint4* F = (const uint4*)feat2;
    float fd[8]; unpack8(F[(size_t)wave * 8 + gl], fd);

    float m = -__builtin_inff(), l = 0.f, a[8];
#pragma unroll
    for (int j = 0; j < 8; ++j) a[j] = 0.f;

    int e0 = start[wave], e1 = start[wave + 1];
    int base = e0;
    for (; base + 16 <= e1; base += 16) {
        int s0 = csr_src[base + grp];
        int s1 = csr_src[base + 8 + grp];
        uint4 u0 = F[(size_t)s0 * 8 + gl];
        uint4 u1 = F[(size_t)s1 * 8 + gl];
        float f0[8], f1[8];
        unpack8(u0, f0); unpack8(u1, f1);
        float p0 = 0.f, p1 = 0.f;
#pragma unroll
        for (int j = 0; j < 8; ++j) { p0 += fd[j] * f0[j]; p1 += fd[j] * f1[j]; }
        p0 += __shfl_xor(p0, 1); p1 += __shfl_xor(p1, 1);
        p0 += __shfl_xor(p0, 2); p1 += __shfl_xor(p1, 2);
        p0 += __shfl_xor(p0, 4); p1 += __shfl_xor(p1, 4);
        {
            float sc = p0 * 0.125f;
            float mn = fmaxf(m, sc);
            float sf = __expf(m - mn), w = __expf(sc - mn);
#pragma unroll
            for (int j = 0; j < 8; ++j) a[j] = a[j] * sf + w * f0[j];
            l = l * sf + w; m = mn;
        }
        {
            float sc = p1 * 0.125f;
            float mn = fmaxf(m, sc);
            float sf = __expf(m - mn), w = __expf(sc - mn);
#pragma unroll
            for (int j = 0; j < 8; ++j) a[j] = a[j] * sf + w * f1[j];
            l = l * sf + w; m = mn;
        }
    }
    for (; base < e1; base += 8) {
        int ed = base + grp;
        bool act = ed < e1;
        int s = act ? csr_src[ed] : 0;
        uint4 u = F[(size_t)s * 8 + gl];
        float fv[8]; unpack8(u, fv);
        float p = 0.f;
#pragma unroll
        for (int j = 0; j < 8; ++j) p += fd[j] * fv[j];
        p += __shfl_xor(p, 1);
        p += __shfl_xor(p, 2);
        p += __shfl_xor(p, 4);
        if (act) {
            float sc = p * 0.125f;
            float mn = fmaxf(m, sc);
            float sf = __expf(m - mn), w = __expf(sc - mn);
#pragma unroll
            for (int j = 0; j < 8; ++j) a[j] = a[j] * sf + w * fv[j];
            l = l * sf + w; m = mn;
        }
    }
#pragma unroll
    for (int off = 8; off <= 32; off <<= 1) {
        float mo = __shfl_xor(m, off), lo = __shfl_xor(l, off);
        float bfr[8];
#pragma unroll
        for (int j = 0; j < 8; ++j) bfr[j] = __shfl_xor(a[j], off);
        float mn = fmaxf(m, mo);
        float sA = (m == mn) ? 1.f : __expf(m - mn);
        float sB = (mo == mn) ? 1.f : __expf(mo - mn);
#pragma unroll
        for (int j = 0; j < 8; ++j) a[j] = a[j] * sA + bfr[j] * sB;
        l = l * sA + lo * sB; m = mn;
    }
    if (grp == 0) {
        float rcp = 1.f / fmaxf(l, 1e-9f);
        float v[8];
#pragma unroll
        for (int j = 0; j < 8; ++j) v[j] = a[j] * rcp;
        if (f) {
            float* op = (float*)out + (size_t)wave * 64 + gl * 8;
            *(float4*)(op)     = (float4){v[0], v[1], v[2], v[3]};
            *(float4*)(op + 4) = (float4){v[4], v[5], v[6], v[7]};
        } else {
            uint4 pk;
            pk.x = (unsigned)f32_to_bf16_raw(v[0]) | ((unsigned)f32_to_bf16_raw(v[1]) << 16);
            pk.y = (unsigned)f32_to_bf16_raw(v[2]) | ((unsigned)f32_to_bf16_raw(v[3]) << 16);
            pk.z = (unsigned)f32_to_bf16_raw(v[4]) | ((unsigned)f32_to_bf16_raw(v[5]) << 16);
            pk.w = (unsigned)f32_to_bf16_raw(v[6]) | ((unsigned)f32_to_bf16_raw(v[7]) << 16);
            *(uint4*)((unsigned short*)out + (size_t)wave * 64 + gl * 8) = pk;
        }
    }
}

extern "C" void kernel_launch(void* const* d_in, const int* in_sizes, int n_in,
                              void* d_out, int out_size, void* d_ws, size_t ws_size,
                              hipStream_t stream) {
    const void* h  = d_in[0];
    const void* W1 = d_in[1];
    const void* W2 = d_in[2];
    const int* src = (const int*)d_in[3];
    const int* dst = (const int*)d_in[4];

    float* ws = (float*)d_ws;
    // Layout (4-byte words), peak ~11.36M words = 45.5 MB:
    //   [0,     3.2M)   feat1 [N,128] bf16       (later: feat2 [N,64] bf16)
    //   [3.2M,  6.4M)   agg1e [N,128] bf16 (ELU applied)
    //   [6.4M,  8.0M)   inter [E] uint (binned packed edges)
    //   [9.6M, 11.2M)   csr_src [E] int
    //   [11.2M,11.26M)  start [N+1] int
    //   [11.33M]        dtype flag
    //   [11.331M]       bcnt[98]; [11.332M] bbase[99]; [11.333M] bcur[98]
    //   [11.34M..]      W1T 128x136 bf16; [11.35M..] W2T 64x136 bf16
    unsigned short* feat1 = (unsigned short*)ws;
    unsigned short* agg1e = (unsigned short*)(ws + 3200000);
    unsigned short* feat2 = (unsigned short*)ws;      // after feat1 dead
    unsigned* inter       = (unsigned*)(ws + 6400000);
    int*   csr_src        = (int*)(ws + 9600000);
    int*   start          = (int*)(ws + 11200000);
    int*   flag           = (int*)(ws + 11330000);
    int*   bcnt           = (int*)(ws + 11331000);
    int*   bbase          = (int*)(ws + 11332000);
    int*   bcur           = (int*)(ws + 11333000);
    unsigned short* W1T   = (unsigned short*)(ws + 11340000);
    unsigned short* W2T   = (unsigned short*)(ws + 11350000);

    detect_dtype_kernel<<<1, 256, 0, stream>>>((const unsigned short*)W1, flag);
    prep_kernel<<<12, 256, 0, stream>>>(W1, W2, W1T, W2T, flag);

    // ---- binned CSR build (by dst), storing src ids ----
    (void)hipMemsetAsync(bcnt, 0, NBUCK * 4, stream);
    bucket_count_kernel<<<NB_A, 256, 0, stream>>>(dst, bcnt, N_EDGES);
    bucket_scan_kernel<<<1, 128, 0, stream>>>(bcnt, bbase, bcur);
    binA_kernel<<<NB_A, 256, 0, stream>>>(src, dst, bcur, inter, N_EDGES);
    binB_kernel<<<NBUCK, 256, 0, stream>>>(inter, bbase, csr_src, start, N_NODES, N_EDGES);

    gemm1_mfma_kernel<<<(N_NODES + 63) / 64, 256, 0, stream>>>(h, W1T, feat1, N_NODES, flag);
    gat1_kernel<<<(N_NODES + 3) / 4, 256, 0, stream>>>(feat1, csr_src, start, agg1e, N_NODES);
    gemm2_mfma_kernel<<<(N_NODES + 63) / 64, 256, 0, stream>>>(agg1e, W2T, feat2, N_NODES);
    gat2_kernel<<<(N_NODES + 3) / 4, 256, 0, stream>>>(feat2, csr_src, start, d_out, N_NODES, flag);
}

// Round 13
// 295.316 us; speedup vs baseline: 61.3290x; 1.0174x over previous
//
#include <hip/hip_runtime.h>
#include <hip/hip_bf16.h>

#define N_NODES 50000
#define N_EDGES 1600000
#define NBUCK 98              // ceil(50000/512) buckets of 512 nodes
#define EPB 4096              // edges per binning block
#define NB_A ((N_EDGES + EPB - 1) / EPB)   // 391

typedef short bf16x8 __attribute__((ext_vector_type(8)));
typedef float f32x4  __attribute__((ext_vector_type(4)));

__device__ __forceinline__ float bf16_raw_to_f32(unsigned short u) {
    return __uint_as_float(((unsigned)u) << 16);
}
__device__ __forceinline__ unsigned short f32_to_bf16_raw(float v) {
    unsigned u = __float_as_uint(v);
    return (unsigned short)((u + 0x7fffu + ((u >> 16) & 1u)) >> 16);
}
__device__ __forceinline__ float load_elem(const void* p, size_t i, int f) {
    if (f) return ((const float*)p)[i];
    return bf16_raw_to_f32(((const unsigned short*)p)[i]);
}
__device__ __forceinline__ void unpack8(uint4 u, float* f) {
    f[0] = __uint_as_float(u.x << 16);
    f[1] = __uint_as_float(u.x & 0xffff0000u);
    f[2] = __uint_as_float(u.y << 16);
    f[3] = __uint_as_float(u.y & 0xffff0000u);
    f[4] = __uint_as_float(u.z << 16);
    f[5] = __uint_as_float(u.z & 0xffff0000u);
    f[6] = __uint_as_float(u.w << 16);
    f[7] = __uint_as_float(u.w & 0xffff0000u);
}

// Online-softmax update, single-exp form. BIT-IDENTICAL to the two-exp
// version: exactly one of {sf,w} is exp(0)=1 there; here t=exp(-|sc-m|) is
// the other. First edge (m=-inf): d=+inf, t=0, up=1 -> sf=0,w=1 (same).
__device__ __forceinline__ void osm_upd(float sc, float& m, float& l,
                                        float* a, const float* fv) {
    float d  = sc - m;
    float t  = __expf(-fabsf(d));
    bool  up = d > 0.f;
    float sf = up ? t : 1.f;
    float w  = up ? 1.f : t;
    if (up) m = sc;
#pragma unroll
    for (int j = 0; j < 8; ++j) a[j] = fmaf(a[j], sf, w * fv[j]);
    l = fmaf(l, sf, w);
}

// ---- dtype probe (verified R4): flag=1 -> fp32 storage. Also zeroes bcnt.
__global__ void detect_dtype_kernel(const unsigned short* __restrict__ w1raw,
                                    int* __restrict__ flag, int* __restrict__ bcnt) {
    __shared__ float red[256];
    if (threadIdx.x < NBUCK) bcnt[threadIdx.x] = 0;
    float mx = 0.f;
    for (int i = threadIdx.x * 2; i < 16384; i += 512) {
        float v = fabsf(bf16_raw_to_f32(w1raw[i]));
        if (!isnan(v)) mx = fmaxf(mx, v);
    }
    red[threadIdx.x] = mx;
    __syncthreads();
    for (int s = 128; s > 0; s >>= 1) {
        if (threadIdx.x < s) red[threadIdx.x] = fmaxf(red[threadIdx.x], red[threadIdx.x + s]);
        __syncthreads();
    }
    if (threadIdx.x == 0) flag[0] = (red[0] > 1e4f) ? 1 : 0;
}

// ---- prep: W1T[n][k] (128x136 bf16), W2T[n][k] (64x136 bf16) ----
#define WPAD 136
__global__ void prep_kernel(const void* __restrict__ W1, const void* __restrict__ W2,
                            unsigned short* __restrict__ W1T,
                            unsigned short* __restrict__ W2T,
                            const int* __restrict__ flag) {
    const int f = *flag;
    int bid = blockIdx.x, tid = threadIdx.x;
    if (bid < 8) {
        int n = bid * 16 + (tid & 15);
        int kb = (tid >> 4) * 8;
        for (int j = 0; j < 8; ++j)
            W1T[n * WPAD + kb + j] = f32_to_bf16_raw(load_elem(W1, (size_t)(kb + j) * 128 + n, f));
    } else {
        int n = (bid - 8) * 16 + (tid & 15);
        int kb = (tid >> 4) * 8;
        for (int j = 0; j < 8; ++j)
            W2T[n * WPAD + kb + j] = f32_to_bf16_raw(load_elem(W2, (size_t)(kb + j) * 64 + n, f));
    }
}

// ============ binned CSR build (R12-proven) ============
__global__ void bucket_count_kernel(const int* __restrict__ dst,
                                    int* __restrict__ bcnt, int E) {
    __shared__ int hist[NBUCK];
    int t = threadIdx.x;
    if (t < NBUCK) hist[t] = 0;
    __syncthreads();
    int e0 = blockIdx.x * EPB;
    for (int k = 0; k < 16; ++k) {
        int e = e0 + k * 256 + t;
        if (e < E) atomicAdd(&hist[dst[e] >> 9], 1);
    }
    __syncthreads();
    if (t < NBUCK && hist[t]) atomicAdd(&bcnt[t], hist[t]);
}

__global__ void bucket_scan_kernel(const int* __restrict__ bcnt,
                                   int* __restrict__ bbase, int* __restrict__ bcur) {
    __shared__ int tmp[128];
    int t = threadIdx.x;
    int v = (t < NBUCK) ? bcnt[t] : 0;
    tmp[t] = v;
    __syncthreads();
    for (int off = 1; off < 128; off <<= 1) {
        int x = (t >= off) ? tmp[t - off] : 0;
        __syncthreads();
        tmp[t] += x;
        __syncthreads();
    }
    if (t < NBUCK) { int ex = tmp[t] - v; bbase[t] = ex; bcur[t] = ex; }
    if (t == NBUCK - 1) bbase[NBUCK] = tmp[t];
}

__global__ void binA_kernel(const int* __restrict__ src, const int* __restrict__ dst,
                            int* __restrict__ bcur, unsigned* __restrict__ inter, int E) {
    __shared__ int hist[NBUCK], gbase[NBUCK], cur[NBUCK];
    int t = threadIdx.x;
    if (t < NBUCK) hist[t] = 0;
    __syncthreads();
    int e0 = blockIdx.x * EPB;
    for (int k = 0; k < 16; ++k) {
        int e = e0 + k * 256 + t;
        if (e < E) atomicAdd(&hist[dst[e] >> 9], 1);
    }
    __syncthreads();
    if (t < NBUCK) {
        int hv = hist[t];
        gbase[t] = hv ? atomicAdd(&bcur[t], hv) : 0;
        cur[t] = 0;
    }
    __syncthreads();
    for (int k = 0; k < 16; ++k) {
        int e = e0 + k * 256 + t;
        if (e < E) {
            int d = dst[e];
            int b = d >> 9;
            int off = atomicAdd(&cur[b], 1);
            inter[gbase[b] + off] = (unsigned)src[e] | ((unsigned)(d & 511) << 16);
        }
    }
}

__global__ void binB_kernel(const unsigned* __restrict__ inter,
                            const int* __restrict__ bbase,
                            int* __restrict__ csr_src, int* __restrict__ start,
                            int N, int E) {
    int b = blockIdx.x;
    int node0 = b << 9;
    int lo = bbase[b], hi = bbase[b + 1];
    __shared__ int hist[512];
    __shared__ int t2[256];
    int t = threadIdx.x;
    hist[t] = 0; hist[t + 256] = 0;
    __syncthreads();
    for (int e = lo + t; e < hi; e += 256) atomicAdd(&hist[inter[e] >> 16], 1);
    __syncthreads();
    int s0 = hist[2 * t], s1 = hist[2 * t + 1];
    t2[t] = s0 + s1;
    __syncthreads();
    for (int off = 1; off < 256; off <<= 1) {
        int x = (t >= off) ? t2[t - off] : 0;
        __syncthreads();
        t2[t] += x;
        __syncthreads();
    }
    int base = (t == 0) ? 0 : t2[t - 1];
    hist[2 * t] = base;
    hist[2 * t + 1] = base + s0;
    __syncthreads();
    int nodeCnt = min(512, N - node0);
    for (int i = t; i < nodeCnt; i += 256) start[node0 + i] = lo + hist[i];
    if (b == NBUCK - 1 && t == 0) start[N] = E;
    __syncthreads();
    for (int e = lo + t; e < hi; e += 256) {
        unsigned u = inter[e];
        int slot = lo + atomicAdd(&hist[u >> 16], 1);
        csr_src[slot] = (int)(u & 0xffffu);
    }
}

// ---- MFMA GEMM1 (R9-proven) ----
__global__ void gemm1_mfma_kernel(const void* __restrict__ h,
                                  const unsigned short* __restrict__ W1T,
                                  unsigned short* __restrict__ feat1, int N,
                                  const int* __restrict__ flag) {
    const int f = *flag;
    int lane = threadIdx.x & 63;
    int rbase = blockIdx.x * 64 + (threadIdx.x >> 6) * 16;
    int arow = rbase + (lane & 15);
    int arowc = min(arow, N - 1);
    int kb0 = (lane >> 4) * 8;

    f32x4 acc[8];
#pragma unroll
    for (int t = 0; t < 8; ++t) acc[t] = (f32x4){0.f, 0.f, 0.f, 0.f};

#pragma unroll
    for (int ks = 0; ks < 4; ++ks) {
        int kb = ks * 32 + kb0;
        bf16x8 afrag;
        if (f == 0) {
            afrag = *(const bf16x8*)((const unsigned short*)h + (size_t)arowc * 128 + kb);
        } else {
            const float* hp = (const float*)h + (size_t)arowc * 128 + kb;
#pragma unroll
            for (int j = 0; j < 8; ++j) afrag[j] = (short)f32_to_bf16_raw(hp[j]);
        }
#pragma unroll
        for (int t = 0; t < 8; ++t) {
            int n = t * 16 + (lane & 15);
            bf16x8 bfrag = *(const bf16x8*)(W1T + n * WPAD + kb);
            acc[t] = __builtin_amdgcn_mfma_f32_16x16x32_bf16(afrag, bfrag, acc[t], 0, 0, 0);
        }
    }
    int orow0 = rbase + (lane >> 4) * 4;
    int col = lane & 15;
#pragma unroll
    for (int t = 0; t < 8; ++t)
#pragma unroll
        for (int r = 0; r < 4; ++r) {
            int row = orow0 + r;
            if (row < N)
                feat1[(size_t)row * 128 + t * 16 + col] = f32_to_bf16_raw(acc[t][r]);
        }
}

// ---- MFMA GEMM2 (R9-proven) ----
__global__ void gemm2_mfma_kernel(const unsigned short* __restrict__ agg1e,
                                  const unsigned short* __restrict__ W2T,
                                  unsigned short* __restrict__ feat2, int N) {
    int lane = threadIdx.x & 63;
    int rbase = blockIdx.x * 64 + (threadIdx.x >> 6) * 16;
    int arow = rbase + (lane & 15);
    int arowc = min(arow, N - 1);
    int kb0 = (lane >> 4) * 8;

    f32x4 acc[4];
#pragma unroll
    for (int t = 0; t < 4; ++t) acc[t] = (f32x4){0.f, 0.f, 0.f, 0.f};

#pragma unroll
    for (int ks = 0; ks < 4; ++ks) {
        int kb = ks * 32 + kb0;
        bf16x8 afrag = *(const bf16x8*)(agg1e + (size_t)arowc * 128 + kb);
#pragma unroll
        for (int t = 0; t < 4; ++t) {
            int n = t * 16 + (lane & 15);
            bf16x8 bfrag = *(const bf16x8*)(W2T + n * WPAD + kb);
            acc[t] = __builtin_amdgcn_mfma_f32_16x16x32_bf16(afrag, bfrag, acc[t], 0, 0, 0);
        }
    }
    int orow0 = rbase + (lane >> 4) * 4;
    int col = lane & 15;
#pragma unroll
    for (int t = 0; t < 4; ++t)
#pragma unroll
        for (int r = 0; r < 4; ++r) {
            int row = orow0 + r;
            if (row < N)
                feat2[(size_t)row * 64 + t * 16 + col] = f32_to_bf16_raw(acc[t][r]);
        }
}

// ======= layer 1 fused GAT: wave = 1 dst; 4 groups x 16 lanes =======
// R13: single-exp update (bit-identical) + 32-bit saddr-form gathers.
__global__ void gat1_kernel(const unsigned short* __restrict__ feat1,
                            const int* __restrict__ csr_src,
                            const int* __restrict__ start,
                            unsigned short* __restrict__ agg1e, int N) {
    int wave = blockIdx.x * 4 + (threadIdx.x >> 6);
    if (wave >= N) return;
    int lane = threadIdx.x & 63;
    int grp = lane >> 4, gl = lane & 15;
    const char* fb = (const char*)feat1;       // uniform base; row = 256 B
    unsigned loff = (unsigned)gl << 4;
    float fd[8];
    unpack8(*(const uint4*)(fb + (((unsigned)wave << 8) + loff)), fd);

    float m = -__builtin_inff(), l = 0.f, a[8];
#pragma unroll
    for (int j = 0; j < 8; ++j) a[j] = 0.f;

    int e0 = start[wave], e1 = start[wave + 1];
    int base = e0;
    for (; base + 8 <= e1; base += 8) {
        int s0 = csr_src[base + grp];
        int s1 = csr_src[base + 4 + grp];
        uint4 u0 = *(const uint4*)(fb + (((unsigned)s0 << 8) + loff));
        uint4 u1 = *(const uint4*)(fb + (((unsigned)s1 << 8) + loff));
        float f0[8], f1[8];
        unpack8(u0, f0); unpack8(u1, f1);
        float p0 = 0.f, p1 = 0.f;
#pragma unroll
        for (int j = 0; j < 8; ++j) { p0 += fd[j] * f0[j]; p1 += fd[j] * f1[j]; }
        p0 += __shfl_xor(p0, 1);               // 16-dim head dot
        p1 += __shfl_xor(p1, 1);
        osm_upd(p0 * 0.25f, m, l, a, f0);
        osm_upd(p1 * 0.25f, m, l, a, f1);
    }
    for (; base < e1; base += 4) {
        int ed = base + grp;
        bool act = ed < e1;
        int s = act ? csr_src[ed] : 0;
        uint4 u = *(const uint4*)(fb + (((unsigned)s << 8) + loff));
        float fv[8]; unpack8(u, fv);
        float p = 0.f;
#pragma unroll
        for (int j = 0; j < 8; ++j) p += fd[j] * fv[j];
        p += __shfl_xor(p, 1);
        if (act) osm_upd(p * 0.25f, m, l, a, fv);
    }
#pragma unroll
    for (int off = 16; off <= 32; off <<= 1) {
        float mo = __shfl_xor(m, off), lo = __shfl_xor(l, off);
        float bfr[8];
#pragma unroll
        for (int j = 0; j < 8; ++j) bfr[j] = __shfl_xor(a[j], off);
        float mn = fmaxf(m, mo);
        float sA = (m == mn) ? 1.f : __expf(m - mn);
        float sB = (mo == mn) ? 1.f : __expf(mo - mn);
#pragma unroll
        for (int j = 0; j < 8; ++j) a[j] = a[j] * sA + bfr[j] * sB;
        l = l * sA + lo * sB; m = mn;
    }
    if (grp == 0) {
        float rcp = 1.f / fmaxf(l, 1e-9f);
        float v[8];
#pragma unroll
        for (int j = 0; j < 8; ++j) {
            float x = a[j] * rcp;
            v[j] = (x > 0.f) ? x : expm1f(x);   // ELU fused
        }
        uint4 pk;
        pk.x = (unsigned)f32_to_bf16_raw(v[0]) | ((unsigned)f32_to_bf16_raw(v[1]) << 16);
        pk.y = (unsigned)f32_to_bf16_raw(v[2]) | ((unsigned)f32_to_bf16_raw(v[3]) << 16);
        pk.z = (unsigned)f32_to_bf16_raw(v[4]) | ((unsigned)f32_to_bf16_raw(v[5]) << 16);
        pk.w = (unsigned)f32_to_bf16_raw(v[6]) | ((unsigned)f32_to_bf16_raw(v[7]) << 16);
        *(uint4*)(agg1e + (size_t)wave * 128 + gl * 8) = pk;
    }
}

// ======= layer 2 fused GAT: wave = 1 dst; 8 groups x 8 lanes =======
__global__ void gat2_kernel(const unsigned short* __restrict__ feat2,
                            const int* __restrict__ csr_src,
                            const int* __restrict__ start,
                            void* __restrict__ out, int N,
                            const int* __restrict__ flag) {
    int wave = blockIdx.x * 4 + (threadIdx.x >> 6);
    if (wave >= N) return;
    int lane = threadIdx.x & 63;
    int grp = lane >> 3, gl = lane & 7;
    const int f = *flag;
    const char* fb = (const char*)feat2;       // uniform base; row = 128 B
    unsigned loff = (unsigned)gl << 4;
    float fd[8];
    unpack8(*(const uint4*)(fb + (((unsigned)wave << 7) + loff)), fd);

    float m = -__builtin_inff(), l = 0.f, a[8];
#pragma unroll
    for (int j = 0; j < 8; ++j) a[j] = 0.f;

    int e0 = start[wave], e1 = start[wave + 1];
    int base = e0;
    for (; base + 16 <= e1; base += 16) {
        int s0 = csr_src[base + grp];
        int s1 = csr_src[base + 8 + grp];
        uint4 u0 = *(const uint4*)(fb + (((unsigned)s0 << 7) + loff));
        uint4 u1 = *(const uint4*)(fb + (((unsigned)s1 << 7) + loff));
        float f0[8], f1[8];
        unpack8(u0, f0); unpack8(u1, f1);
        float p0 = 0.f, p1 = 0.f;
#pragma unroll
        for (int j = 0; j < 8; ++j) { p0 += fd[j] * f0[j]; p1 += fd[j] * f1[j]; }
        p0 += __shfl_xor(p0, 1); p1 += __shfl_xor(p1, 1);
        p0 += __shfl_xor(p0, 2); p1 += __shfl_xor(p1, 2);
        p0 += __shfl_xor(p0, 4); p1 += __shfl_xor(p1, 4);
        osm_upd(p0 * 0.125f, m, l, a, f0);
        osm_upd(p1 * 0.125f, m, l, a, f1);
    }
    for (; base < e1; base += 8) {
        int ed = base + grp;
        bool act = ed < e1;
        int s = act ? csr_src[ed] : 0;
        uint4 u = *(const uint4*)(fb + (((unsigned)s << 7) + loff));
        float fv[8]; unpack8(u, fv);
        float p = 0.f;
#pragma unroll
        for (int j = 0; j < 8; ++j) p += fd[j] * fv[j];
        p += __shfl_xor(p, 1);
        p += __shfl_xor(p, 2);
        p += __shfl_xor(p, 4);
        if (act) osm_upd(p * 0.125f, m, l, a, fv);
    }
#pragma unroll
    for (int off = 8; off <= 32; off <<= 1) {
        float mo = __shfl_xor(m, off), lo = __shfl_xor(l, off);
        float bfr[8];
#pragma unroll
        for (int j = 0; j < 8; ++j) bfr[j] = __shfl_xor(a[j], off);
        float mn = fmaxf(m, mo);
        float sA = (m == mn) ? 1.f : __expf(m - mn);
        float sB = (mo == mn) ? 1.f : __expf(mo - mn);
#pragma unroll
        for (int j = 0; j < 8; ++j) a[j] = a[j] * sA + bfr[j] * sB;
        l = l * sA + lo * sB; m = mn;
    }
    if (grp == 0) {
        float rcp = 1.f / fmaxf(l, 1e-9f);
        float v[8];
#pragma unroll
        for (int j = 0; j < 8; ++j) v[j] = a[j] * rcp;
        if (f) {
            float* op = (float*)out + (size_t)wave * 64 + gl * 8;
            *(float4*)(op)     = (float4){v[0], v[1], v[2], v[3]};
            *(float4*)(op + 4) = (float4){v[4], v[5], v[6], v[7]};
        } else {
            uint4 pk;
            pk.x = (unsigned)f32_to_bf16_raw(v[0]) | ((unsigned)f32_to_bf16_raw(v[1]) << 16);
            pk.y = (unsigned)f32_to_bf16_raw(v[2]) | ((unsigned)f32_to_bf16_raw(v[3]) << 16);
            pk.z = (unsigned)f32_to_bf16_raw(v[4]) | ((unsigned)f32_to_bf16_raw(v[5]) << 16);
            pk.w = (unsigned)f32_to_bf16_raw(v[6]) | ((unsigned)f32_to_bf16_raw(v[7]) << 16);
            *(uint4*)((unsigned short*)out + (size_t)wave * 64 + gl * 8) = pk;
        }
    }
}

extern "C" void kernel_launch(void* const* d_in, const int* in_sizes, int n_in,
                              void* d_out, int out_size, void* d_ws, size_t ws_size,
                              hipStream_t stream) {
    const void* h  = d_in[0];
    const void* W1 = d_in[1];
    const void* W2 = d_in[2];
    const int* src = (const int*)d_in[3];
    const int* dst = (const int*)d_in[4];

    float* ws = (float*)d_ws;
    // Layout (4-byte words), peak ~11.36M words = 45.5 MB (same as R12)
    unsigned short* feat1 = (unsigned short*)ws;
    unsigned short* agg1e = (unsigned short*)(ws + 3200000);
    unsigned short* feat2 = (unsigned short*)ws;      // after feat1 dead
    unsigned* inter       = (unsigned*)(ws + 6400000);
    int*   csr_src        = (int*)(ws + 9600000);
    int*   start          = (int*)(ws + 11200000);
    int*   flag           = (int*)(ws + 11330000);
    int*   bcnt           = (int*)(ws + 11331000);
    int*   bbase          = (int*)(ws + 11332000);
    int*   bcur           = (int*)(ws + 11333000);
    unsigned short* W1T   = (unsigned short*)(ws + 11340000);
    unsigned short* W2T   = (unsigned short*)(ws + 11350000);

    detect_dtype_kernel<<<1, 256, 0, stream>>>((const unsigned short*)W1, flag, bcnt);
    prep_kernel<<<12, 256, 0, stream>>>(W1, W2, W1T, W2T, flag);

    // ---- binned CSR build (by dst), storing src ids ----
    bucket_count_kernel<<<NB_A, 256, 0, stream>>>(dst, bcnt, N_EDGES);
    bucket_scan_kernel<<<1, 128, 0, stream>>>(bcnt, bbase, bcur);
    binA_kernel<<<NB_A, 256, 0, stream>>>(src, dst, bcur, inter, N_EDGES);
    binB_kernel<<<NBUCK, 256, 0, stream>>>(inter, bbase, csr_src, start, N_NODES, N_EDGES);

    gemm1_mfma_kernel<<<(N_NODES + 63) / 64, 256, 0, stream>>>(h, W1T, feat1, N_NODES, flag);
    gat1_kernel<<<(N_NODES + 3) / 4, 256, 0, stream>>>(feat1, csr_src, start, agg1e, N_NODES);
    gemm2_mfma_kernel<<<(N_NODES + 63) / 64, 256, 0, stream>>>(agg1e, W2T, feat2, N_NODES);
    gat2_kernel<<<(N_NODES + 3) / 4, 256, 0, stream>>>(feat2, csr_src, start, d_out, N_NODES, flag);
}